// Round 1
// baseline (3936.244 us; speedup 1.0000x reference)
//
#include <hip/hip_runtime.h>

#define H_  1024
#define W_  1024
#define HW_ (H_*W_)
#define M_  524288

#define SWZ(a) ((a) + ((a)>>4))

// ---------------------------------------------------------------- complex mul
__device__ __forceinline__ float2 cmulf(float2 a, float2 b){
  return make_float2(fmaf(a.x,b.x,-(a.y*b.y)), fmaf(a.x,b.y,a.y*b.x));
}

// ---------------------------------------------------------------- radix-4 bfly
template<int DIR>
__device__ __forceinline__ void bfly4(float2 v[4], int j, int Ns){
  if (Ns>1){
    float ang = ((DIR>0)?6.28318530717958647692f:-6.28318530717958647692f)
                * (float)(j&(Ns-1)) / (float)(4*Ns);
    float s,c; __sincosf(ang,&s,&c);
    float2 w1=make_float2(c,s);
    float2 w2=cmulf(w1,w1);
    float2 w3=cmulf(w2,w1);
    v[1]=cmulf(v[1],w1); v[2]=cmulf(v[2],w2); v[3]=cmulf(v[3],w3);
  }
  float2 t0=make_float2(v[0].x+v[2].x, v[0].y+v[2].y);
  float2 t2=make_float2(v[0].x-v[2].x, v[0].y-v[2].y);
  float2 t1=make_float2(v[1].x+v[3].x, v[1].y+v[3].y);
  float2 t3=make_float2(v[1].x-v[3].x, v[1].y-v[3].y);
  float2 t3r=(DIR<0)?make_float2(t3.y,-t3.x):make_float2(-t3.y,t3.x);
  v[0]=make_float2(t0.x+t1.x,  t0.y+t1.y);
  v[1]=make_float2(t2.x+t3r.x, t2.y+t3r.y);
  v[2]=make_float2(t0.x-t1.x,  t0.y-t1.y);
  v[3]=make_float2(t2.x-t3r.x, t2.y-t3r.y);
}

template<int DIR, int NS>
__device__ __forceinline__ void fft_stage(int j, const float2* src, float2* dst){
  float2 v[4];
#pragma unroll
  for(int r=0;r<4;r++) v[r]=src[SWZ(j+256*r)];
  bfly4<DIR>(v,j,NS);
  int base = ((j & ~(NS-1))<<2) | (j&(NS-1));
#pragma unroll
  for(int r=0;r<4;r++) dst[SWZ(base+NS*r)]=v[r];
}

// 1024-pt Stockham FFT; v holds x[j], x[j+256], x[j+512], x[j+768] on entry;
// on exit v[r] is output element (j + 256*r), scaled.
template<int DIR>
__device__ __forceinline__ void fft1024_core(float2 v[4], int j, float2* A, float2* B, float scale){
  bfly4<DIR>(v,j,1);
#pragma unroll
  for(int r=0;r<4;r++) A[SWZ(4*j+r)]=v[r];
  __syncthreads();
  fft_stage<DIR,4 >(j,A,B); __syncthreads();
  fft_stage<DIR,16>(j,B,A); __syncthreads();
  fft_stage<DIR,64>(j,A,B); __syncthreads();
#pragma unroll
  for(int r=0;r<4;r++) v[r]=B[SWZ(j+256*r)];
  bfly4<DIR>(v,j,256);
#pragma unroll
  for(int r=0;r<4;r++){ v[r].x*=scale; v[r].y*=scale; }
}

// FFT along contiguous axis (axis 1). src may equal dst (block owns its row).
template<int DIR>
__global__ __launch_bounds__(256) void k_fft_rows(const float2* src, float2* dst, float scale){
  __shared__ float2 A[1088], B[1088];
  int j = threadIdx.x;
  const float2* s = src + (size_t)blockIdx.x*W_;
  float2 v[4];
#pragma unroll
  for(int r=0;r<4;r++) v[r]=s[j+256*r];
  fft1024_core<DIR>(v,j,A,B,scale);
  float2* d = dst + (size_t)blockIdx.x*W_;
#pragma unroll
  for(int r=0;r<4;r++) d[j+256*r]=v[r];
}

// FFT along axis 0, in-place, 4 columns per block via LDS tile.
template<int DIR>
__global__ __launch_bounds__(256) void k_fft_cols(float2* data, float scale){
  __shared__ float2 T[4*1025];
  __shared__ float2 A[1088], B[1088];
  int tid=threadIdx.x, c0=blockIdx.x*4;
#pragma unroll
  for(int k=0;k<16;k++){
    int idx=tid+256*k; int c=idx&3, r=idx>>2;
    T[c*1025+r]=data[(size_t)r*W_ + c0 + c];
  }
  __syncthreads();
  for(int c=0;c<4;c++){
    float2* col = T + c*1025;
    float2 v[4];
#pragma unroll
    for(int r=0;r<4;r++) v[r]=col[tid+256*r];
    fft1024_core<DIR>(v,tid,A,B,scale);
#pragma unroll
    for(int r=0;r<4;r++) col[tid+256*r]=v[r];
  }
  __syncthreads();
#pragma unroll
  for(int k=0;k<16;k++){
    int idx=tid+256*k; int c=idx&3, r=idx>>2;
    data[(size_t)r*W_ + c0 + c]=T[c*1025+r];
  }
}

// ---------------------------------------------------------------- interp
__device__ __forceinline__ void corners(float kx, float ky, int idx[4], float w[4]){
  float gx = kx*1024.f, gy = ky*1024.f;
  float fx = floorf(gx), fy = floorf(gy);
  float tx = gx-fx, ty = gy-fy;
  int ix = ((int)fx)&1023, iy = ((int)fy)&1023;
  int ix1=(ix+1)&1023, iy1=(iy+1)&1023;
  idx[0]=(ix<<10)|iy;  idx[1]=(ix1<<10)|iy;
  idx[2]=(ix<<10)|iy1; idx[3]=(ix1<<10)|iy1;
  float ux=1.f-tx, uy=1.f-ty;
  w[0]=ux*uy; w[1]=tx*uy; w[2]=ux*ty; w[3]=tx*ty;
}

// chain: t_0 = dot_0 ; t_n = dot_n/(sqrt(t_{n-1})+1e-12)
__device__ __forceinline__ float chain_t(const float* t, int n){
  float tv = t[0];
  for(int k=1;k<=n;k++) tv = t[k]/(sqrtf(tv)+1e-12f);
  return tv;
}

// ---------------------------------------------------------------- init kernels
__global__ __launch_bounds__(256) void k_pack(const float* xr, const float* xi, float2* X, float* t){
  int i = blockIdx.x*256+threadIdx.x;
  if (i<HW_) X[i]=make_float2(xr[i],xi[i]);
  if (blockIdx.x==0 && threadIdx.x<16) t[threadIdx.x]=0.f;
}

// av0 = gather(fft2(ones)) = 1024 * (weights touching cell (0,0)); also maxr.
__global__ __launch_bounds__(256) void k_init(const float* kt, float2* kdat, float* t){
  int m = blockIdx.x*256+threadIdx.x;
  float r = 0.f;
  if (m < M_){
    float kx=kt[2*m], ky=kt[2*m+1];
    float dx=kx-0.5f, dy=ky-0.5f;
    r = sqrtf(dx*dx+dy*dy);
    int idx[4]; float w[4];
    corners(kx,ky,idx,w);
    float s=0.f;
#pragma unroll
    for(int q=0;q<4;q++) if (idx[q]==0) s+=w[q];
    kdat[m]=make_float2(1024.f*s,0.f);
  }
  for(int o=32;o>0;o>>=1) r = fmaxf(r, __shfl_down(r,o,64));
  __shared__ float sm[4];
  if((threadIdx.x&63)==0) sm[threadIdx.x>>6]=r;
  __syncthreads();
  if(threadIdx.x==0){
    r = fmaxf(fmaxf(sm[0],sm[1]),fmaxf(sm[2],sm[3]));
    atomicMax((int*)(t+15), __float_as_int(r));
  }
}

// ---------------------------------------------------------------- scatter
// G += w * (kdat * scale); scale = c_n from chain (power), or 1 (chain_n<=0)
__global__ __launch_bounds__(256) void k_scatter(const float2* kdat, const float* kt,
                                                 float* G, const float* t, int chain_n){
  int m = blockIdx.x*256+threadIdx.x;
  if (m>=M_) return;
  float sc = 1.f;
  if (chain_n>0) sc = 1.f/(sqrtf(chain_t(t,chain_n-1))+1e-12f);
  float2 v = kdat[m];
  float vx=v.x*sc, vy=v.y*sc;
  int idx[4]; float w[4];
  corners(kt[2*m],kt[2*m+1],idx,w);
#pragma unroll
  for(int q=0;q<4;q++){
    atomicAdd(G+2*idx[q],   w[q]*vx);
    atomicAdd(G+2*idx[q]+1, w[q]*vy);
  }
}

// ---------------------------------------------------------------- power gather
// kdat <- gather(G) (unnormalized); dot_n = <new, old> -> t[n]; if last: ssq -> t[10]
__global__ __launch_bounds__(256) void k_gather_pow(const float2* G, const float* kt,
                                                    float2* kdat, float* t, int n, int last){
  int m = blockIdx.x*256+threadIdx.x;
  float dot=0.f, ssq=0.f;
  if (m<M_){
    int idx[4]; float w[4];
    corners(kt[2*m],kt[2*m+1],idx,w);
    float sx=0.f, sy=0.f;
#pragma unroll
    for(int q=0;q<4;q++){ float2 g=G[idx[q]]; sx=fmaf(w[q],g.x,sx); sy=fmaf(w[q],g.y,sy); }
    float2 old = kdat[m];
    dot = sx*old.x + sy*old.y;
    ssq = sx*sx + sy*sy;
    kdat[m]=make_float2(sx,sy);
  }
  __shared__ float sm[4];
  for(int o=32;o>0;o>>=1) dot += __shfl_down(dot,o,64);
  if((threadIdx.x&63)==0) sm[threadIdx.x>>6]=dot;
  __syncthreads();
  if(threadIdx.x==0) atomicAdd(t+n, sm[0]+sm[1]+sm[2]+sm[3]);
  if (last){
    __syncthreads();
    for(int o=32;o>0;o>>=1) ssq += __shfl_down(ssq,o,64);
    if((threadIdx.x&63)==0) sm[threadIdx.x>>6]=ssq;
    __syncthreads();
    if(threadIdx.x==0) atomicAdd(t+10, sm[0]+sm[1]+sm[2]+sm[3]);
  }
}

// ---------------------------------------------------------------- npcg gather
__global__ __launch_bounds__(256) void k_gather_sub(const float2* G, const float* kt,
                                                    const float* kre, const float* kim,
                                                    const float* t, float2* kdat){
  int m = blockIdx.x*256+threadIdx.x;
  if (m>=M_) return;
  float kx=kt[2*m], ky=kt[2*m+1];
  int idx[4]; float w[4];
  corners(kx,ky,idx,w);
  float sx=0.f, sy=0.f;
#pragma unroll
  for(int q=0;q<4;q++){ float2 g=G[idx[q]]; sx=fmaf(w[q],g.x,sx); sy=fmaf(w[q],g.y,sy); }
  float dx=kx-0.5f, dy=ky-0.5f;
  float r=sqrtf(dx*dx+dy*dy);
  float dcf = sqrtf(r/(t[15]+1e-8f));
  kdat[m]=make_float2(sx - kre[m]*dcf, sy - kim[m]*dcf);
}

// ---------------------------------------------------------------- fused CNN + update
// xout = x - w_reg*res - cnn(x) ; 64x64 tile per block, 16x16 blocks
#define XT_S 76
#define XT_P (70*76)
__global__ __launch_bounds__(256) void k_cnn(const float2* __restrict__ x, const float2* __restrict__ res,
    const float* __restrict__ w1, const float* __restrict__ b1,
    const float* __restrict__ w2, const float* __restrict__ b2,
    const float* __restrict__ wraw, const float* __restrict__ t, float2* __restrict__ xout){
  __shared__ __align__(16) float xt[2*XT_P];   // 2ch x 70 rows x stride 76
  __shared__ __align__(16) float ht[68*XT_S];  // 68 rows x stride 76
  int tid = threadIdx.x;
  int ty0 = (blockIdx.x>>4)<<6, tx0 = (blockIdx.x&15)<<6;

  for (int p=tid; p<70*70; p+=256){
    int r=p/70, c=p-r*70;
    int gy=ty0-2+r, gx=tx0-2+c;
    float vx=0.f, vy=0.f;
    if ((unsigned)gy<1024u && (unsigned)gx<1024u){
      float2 v = x[(size_t)gy*W_+gx]; vx=v.x; vy=v.y;
    }
    xt[r*XT_S+c]=vx; xt[XT_P + r*XT_S+c]=vy;
  }
  float acc0[16], acc1[16];
#pragma unroll
  for(int q=0;q<16;q++){ acc0[q]=0.f; acc1[q]=0.f; }
  int oby = tid>>4, obx = tid&15;
  __syncthreads();

  for (int cm=0; cm<32; cm++){
    // ---- conv1: mid channel cm over 68x68 h grid (17x17 blocks of 4x4)
    const float* W1 = w1 + cm*18;        // [ch][ky][kx]
    float b1v = b1[cm];
    for (int b=tid; b<289; b+=256){
      int by=b/17, bx=b-by*17;
      float h[4][4];
#pragma unroll
      for(int i=0;i<4;i++)
#pragma unroll
        for(int j=0;j<4;j++) h[i][j]=b1v;
#pragma unroll
      for (int l=0;l<6;l++){
        int rw = 4*by+l;
        const float* p0 = &xt[rw*XT_S + 4*bx];
        const float* p1 = p0 + XT_P;
        float4 a0 = *(const float4*)p0; float2 a1 = *(const float2*)(p0+4);
        float4 c0 = *(const float4*)p1; float2 c1 = *(const float2*)(p1+4);
        float f0[6]={a0.x,a0.y,a0.z,a0.w,a1.x,a1.y};
        float f1[6]={c0.x,c0.y,c0.z,c0.w,c1.x,c1.y};
#pragma unroll
        for(int i=0;i<4;i++){
          int dy = l-i;
          if (dy<0||dy>2) continue;
#pragma unroll
          for(int j=0;j<4;j++){
            float s=h[i][j];
#pragma unroll
            for(int dx=0;dx<3;dx++){
              s = fmaf(W1[dy*3+dx],   f0[j+dx], s);
              s = fmaf(W1[9+dy*3+dx], f1[j+dx], s);
            }
            h[i][j]=s;
          }
        }
      }
#pragma unroll
      for(int i=0;i<4;i++){
        int gy = ty0 + 4*by-1+i;
#pragma unroll
        for(int j=0;j<4;j++){
          int gx = tx0 + 4*bx-1+j;
          if ((unsigned)gy>=1024u || (unsigned)gx>=1024u) h[i][j]=0.f;
        }
        *(float4*)&ht[(4*by+i)*XT_S + 4*bx] = make_float4(h[i][0],h[i][1],h[i][2],h[i][3]);
      }
    }
    __syncthreads();
    // ---- conv2 accumulate (each thread: 4x4 outputs at (4*oby, 4*obx))
    const float* W2a = w2 + cm*9;        // och 0
    const float* W2b = w2 + (32+cm)*9;   // och 1
#pragma unroll
    for (int l=0;l<6;l++){
      const float* p = &ht[(4*oby+l)*XT_S + 4*obx];
      float4 a=*(const float4*)p; float2 bb=*(const float2*)(p+4);
      float f[6]={a.x,a.y,a.z,a.w,bb.x,bb.y};
#pragma unroll
      for(int i=0;i<4;i++){
        int ky = l-i;
        if (ky<0||ky>2) continue;
#pragma unroll
        for(int j=0;j<4;j++){
          float sA=0.f, sB=0.f;
#pragma unroll
          for(int kx=0;kx<3;kx++){
            sA = fmaf(W2a[ky*3+kx], f[j+kx], sA);
            sB = fmaf(W2b[ky*3+kx], f[j+kx], sB);
          }
          acc0[i*4+j]+=sA; acc1[i*4+j]+=sB;
        }
      }
    }
    __syncthreads();
  }

  // ---- epilogue: w_reg from scalar chain, x - w_reg*res - xnn
  float t8 = chain_t(t,8);
  float c9 = 1.f/(sqrtf(t8)+1e-12f);
  float avn = c9*sqrtf(t[10]);            // ||av_9||
  float vn  = sqrtf(t8)*c9;               // ||v_9||
  float opn = avn/(vn+1e-12f);
  float sig = 1.f/(1.f+__expf(-wraw[0]));
  float wreg = 2.f*sig/(opn*opn);
  float b20=b2[0], b21=b2[1];
#pragma unroll
  for(int i=0;i<4;i++){
    int oy=4*oby+i, gy=ty0+oy;
#pragma unroll
    for(int j=0;j<4;j++){
      int ox=4*obx+j, gx=tx0+ox;
      float xr_ = xt[(oy+2)*XT_S+ox+2];
      float xi_ = xt[XT_P + (oy+2)*XT_S+ox+2];
      float2 rv = res[(size_t)gy*W_+gx];
      float o0 = acc0[i*4+j]+b20;
      float o1 = acc1[i*4+j]+b21;
      xout[(size_t)gy*W_+gx] = make_float2(xr_ - wreg*rv.x - o0,
                                           xi_ - wreg*rv.y - o1);
    }
  }
}

__global__ __launch_bounds__(256) void k_unpack(const float2* X, float* out){
  int i = blockIdx.x*256+threadIdx.x;
  if (i<HW_){ out[i]=X[i].x; out[HW_+i]=X[i].y; }
}

// ================================================================ launch
extern "C" void kernel_launch(void* const* d_in, const int* in_sizes, int n_in,
                              void* d_out, int out_size, void* d_ws, size_t ws_size,
                              hipStream_t stream){
  (void)in_sizes; (void)n_in; (void)out_size; (void)ws_size;
  const float* xr  =(const float*)d_in[0];
  const float* xi  =(const float*)d_in[1];
  const float* kre =(const float*)d_in[2];
  const float* kim =(const float*)d_in[3];
  const float* kt  =(const float*)d_in[4];
  const float* wraw=(const float*)d_in[5];
  const float* w1  =(const float*)d_in[6];
  const float* b1  =(const float*)d_in[7];
  const float* w2  =(const float*)d_in[8];
  const float* b2  =(const float*)d_in[9];
  float* out = (float*)d_out;

  char* ws=(char*)d_ws;
  float2* Wx0 =(float2*)(ws);
  float2* Wx1 =(float2*)(ws + ((size_t)8<<20));
  float2* WF  =(float2*)(ws + ((size_t)16<<20));
  float2* kdat=(float2*)(ws + ((size_t)24<<20));
  float*  t   =(float*) (ws + ((size_t)28<<20));
  const size_t gridBytes = (size_t)HW_*sizeof(float2);
  const float SC = 0.03125f;   // 1/32 per 1-D ortho pass

  k_pack<<<HW_/256,256,0,stream>>>(xr,xi,Wx0,t);
  k_init<<<M_/256,256,0,stream>>>(kt,kdat,t);

  // power iteration, fully in k-space (fft2/ifft2 cancel; Parseval for norms)
  for (int n=0;n<9;n++){
    hipMemsetAsync(WF,0,gridBytes,stream);
    k_scatter<<<M_/256,256,0,stream>>>(kdat,kt,(float*)WF,t,n);
    k_gather_pow<<<M_/256,256,0,stream>>>(WF,kt,kdat,t,n,(n==8)?1:0);
  }

  // npcg = 4 PGD iterations
  for (int it=0; it<4; it++){
    float2* xin  = (it&1)? Wx1 : Wx0;
    float2* xout = (it&1)? Wx0 : Wx1;
    k_fft_rows<-1><<<H_,256,0,stream>>>(xin,WF,SC);
    k_fft_cols<-1><<<W_/4,256,0,stream>>>(WF,SC);
    k_gather_sub<<<M_/256,256,0,stream>>>(WF,kt,kre,kim,t,kdat);
    hipMemsetAsync(WF,0,gridBytes,stream);
    k_scatter<<<M_/256,256,0,stream>>>(kdat,kt,(float*)WF,t,-1);
    k_fft_rows<1><<<H_,256,0,stream>>>(WF,WF,SC);
    k_fft_cols<1><<<W_/4,256,0,stream>>>(WF,SC);
    k_cnn<<<256,256,0,stream>>>(xin,WF,w1,b1,w2,b2,wraw,t,xout);
  }
  k_unpack<<<HW_/256,256,0,stream>>>(Wx0,out);
}

// Round 2
// 1335.447 us; speedup vs baseline: 2.9475x; 2.9475x over previous
//
#include <hip/hip_runtime.h>

#define H_  1024
#define W_  1024
#define HW_ (H_*W_)
#define M_  524288

#define SWZ(a) ((a) + ((a)>>4))

// ---------------------------------------------------------------- complex mul
__device__ __forceinline__ float2 cmulf(float2 a, float2 b){
  return make_float2(fmaf(a.x,b.x,-(a.y*b.y)), fmaf(a.x,b.y,a.y*b.x));
}

// ---------------------------------------------------------------- radix-4 bfly
template<int DIR>
__device__ __forceinline__ void bfly4(float2 v[4], int j, int Ns){
  if (Ns>1){
    float ang = ((DIR>0)?6.28318530717958647692f:-6.28318530717958647692f)
                * (float)(j&(Ns-1)) / (float)(4*Ns);
    float s,c; __sincosf(ang,&s,&c);
    float2 w1=make_float2(c,s);
    float2 w2=cmulf(w1,w1);
    float2 w3=cmulf(w2,w1);
    v[1]=cmulf(v[1],w1); v[2]=cmulf(v[2],w2); v[3]=cmulf(v[3],w3);
  }
  float2 t0=make_float2(v[0].x+v[2].x, v[0].y+v[2].y);
  float2 t2=make_float2(v[0].x-v[2].x, v[0].y-v[2].y);
  float2 t1=make_float2(v[1].x+v[3].x, v[1].y+v[3].y);
  float2 t3=make_float2(v[1].x-v[3].x, v[1].y-v[3].y);
  float2 t3r=(DIR<0)?make_float2(t3.y,-t3.x):make_float2(-t3.y,t3.x);
  v[0]=make_float2(t0.x+t1.x,  t0.y+t1.y);
  v[1]=make_float2(t2.x+t3r.x, t2.y+t3r.y);
  v[2]=make_float2(t0.x-t1.x,  t0.y-t1.y);
  v[3]=make_float2(t2.x-t3r.x, t2.y-t3r.y);
}

template<int DIR, int NS>
__device__ __forceinline__ void fft_stage(int j, const float2* src, float2* dst){
  float2 v[4];
#pragma unroll
  for(int r=0;r<4;r++) v[r]=src[SWZ(j+256*r)];
  bfly4<DIR>(v,j,NS);
  int base = ((j & ~(NS-1))<<2) | (j&(NS-1));
#pragma unroll
  for(int r=0;r<4;r++) dst[SWZ(base+NS*r)]=v[r];
}

template<int DIR>
__device__ __forceinline__ void fft1024_core(float2 v[4], int j, float2* A, float2* B, float scale){
  bfly4<DIR>(v,j,1);
#pragma unroll
  for(int r=0;r<4;r++) A[SWZ(4*j+r)]=v[r];
  __syncthreads();
  fft_stage<DIR,4 >(j,A,B); __syncthreads();
  fft_stage<DIR,16>(j,B,A); __syncthreads();
  fft_stage<DIR,64>(j,A,B); __syncthreads();
#pragma unroll
  for(int r=0;r<4;r++) v[r]=B[SWZ(j+256*r)];
  bfly4<DIR>(v,j,256);
#pragma unroll
  for(int r=0;r<4;r++){ v[r].x*=scale; v[r].y*=scale; }
}

template<int DIR>
__global__ __launch_bounds__(256) void k_fft_rows(const float2* src, float2* dst, float scale){
  __shared__ float2 A[1088], B[1088];
  int j = threadIdx.x;
  const float2* s = src + (size_t)blockIdx.x*W_;
  float2 v[4];
#pragma unroll
  for(int r=0;r<4;r++) v[r]=s[j+256*r];
  fft1024_core<DIR>(v,j,A,B,scale);
  float2* d = dst + (size_t)blockIdx.x*W_;
#pragma unroll
  for(int r=0;r<4;r++) d[j+256*r]=v[r];
}

template<int DIR>
__global__ __launch_bounds__(256) void k_fft_cols(float2* data, float scale){
  __shared__ float2 T[4*1025];
  __shared__ float2 A[1088], B[1088];
  int tid=threadIdx.x, c0=blockIdx.x*4;
#pragma unroll
  for(int k=0;k<16;k++){
    int idx=tid+256*k; int c=idx&3, r=idx>>2;
    T[c*1025+r]=data[(size_t)r*W_ + c0 + c];
  }
  __syncthreads();
  for(int c=0;c<4;c++){
    float2* col = T + c*1025;
    float2 v[4];
#pragma unroll
    for(int r=0;r<4;r++) v[r]=col[tid+256*r];
    fft1024_core<DIR>(v,tid,A,B,scale);
#pragma unroll
    for(int r=0;r<4;r++) col[tid+256*r]=v[r];
  }
  __syncthreads();
#pragma unroll
  for(int k=0;k<16;k++){
    int idx=tid+256*k; int c=idx&3, r=idx>>2;
    data[(size_t)r*W_ + c0 + c]=T[c*1025+r];
  }
}

// ---------------------------------------------------------------- interp helpers
__device__ __forceinline__ void corners(float kx, float ky, int idx[4], float w[4]){
  float gx = kx*1024.f, gy = ky*1024.f;
  float fx = floorf(gx), fy = floorf(gy);
  float tx = gx-fx, ty = gy-fy;
  int ix = ((int)fx)&1023, iy = ((int)fy)&1023;
  int ix1=(ix+1)&1023, iy1=(iy+1)&1023;
  idx[0]=(ix<<10)|iy;  idx[1]=(ix1<<10)|iy;
  idx[2]=(ix<<10)|iy1; idx[3]=(ix1<<10)|iy1;
  float ux=1.f-tx, uy=1.f-ty;
  w[0]=ux*uy; w[1]=tx*uy; w[2]=ux*ty; w[3]=tx*ty;
}

// chain: t_0 = dot_0 ; t_n = dot_n/(sqrt(t_{n-1})+1e-12)
__device__ __forceinline__ float chain_t(const float* t, int n){
  float tv = t[0];
  for(int k=1;k<=n;k++) tv = t[k]/(sqrtf(tv)+1e-12f);
  return tv;
}

// ---------------------------------------------------------------- init
__global__ __launch_bounds__(256) void k_pack(const float* xr, const float* xi, float2* X, float* t){
  int i = blockIdx.x*256+threadIdx.x;
  if (i<HW_) X[i]=make_float2(xr[i],xi[i]);
  if (blockIdx.x==0 && threadIdx.x<16) t[threadIdx.x]=0.f;
}

// histogram by base cell + max radius
__global__ __launch_bounds__(256) void k_hist(const float* kt, int* counts, float* t){
  int m = blockIdx.x*256+threadIdx.x;
  float r = 0.f;
  if (m < M_){
    float kx=kt[2*m], ky=kt[2*m+1];
    float dx=kx-0.5f, dy=ky-0.5f;
    r = sqrtf(dx*dx+dy*dy);
    int ix = ((int)floorf(kx*1024.f))&1023;
    int iy = ((int)floorf(ky*1024.f))&1023;
    atomicAdd(&counts[(ix<<10)|iy],1);
  }
  for(int o=32;o>0;o>>=1) r = fmaxf(r, __shfl_down(r,o,64));
  __shared__ float sm[4];
  if((threadIdx.x&63)==0) sm[threadIdx.x>>6]=r;
  __syncthreads();
  if(threadIdx.x==0){
    r = fmaxf(fmaxf(sm[0],sm[1]),fmaxf(sm[2],sm[3]));
    atomicMax((int*)(t+15), __float_as_int(r));
  }
}

// ---------------------------------------------------------------- scan (1M = 1024 blocks x 1024)
__global__ __launch_bounds__(256) void k_scan1(const int* cnt, int* off, int* bsum){
  __shared__ int sm[256];
  int base = blockIdx.x*1024;
  int tid = threadIdx.x;
  int4 c = *(const int4*)(cnt + base + tid*4);
  int s = c.x+c.y+c.z+c.w;
  sm[tid]=s; __syncthreads();
  int v=s;
  for(int o=1;o<256;o<<=1){
    int u = (tid>=o)? sm[tid-o]:0;
    __syncthreads();
    v += u; sm[tid]=v;
    __syncthreads();
  }
  int excl = v - s;
  int4 o4;
  o4.x=excl; o4.y=excl+c.x; o4.z=excl+c.x+c.y; o4.w=excl+c.x+c.y+c.z;
  *(int4*)(off+base+tid*4)=o4;
  if (tid==255) bsum[blockIdx.x]=v;
}

__global__ __launch_bounds__(256) void k_scan2(int* bsum){
  __shared__ int sm[256];
  int tid=threadIdx.x;
  int4 c = *(const int4*)(bsum + tid*4);
  int s = c.x+c.y+c.z+c.w;
  sm[tid]=s; __syncthreads();
  int v=s;
  for(int o=1;o<256;o<<=1){
    int u = (tid>=o)? sm[tid-o]:0;
    __syncthreads();
    v += u; sm[tid]=v;
    __syncthreads();
  }
  int excl=v-s;
  int4 o4;
  o4.x=excl; o4.y=excl+c.x; o4.z=excl+c.x+c.y; o4.w=excl+c.x+c.y+c.z;
  *(int4*)(bsum+tid*4)=o4;
}

__global__ __launch_bounds__(256) void k_scan3(int* off, const int* bbase){
  int gid = blockIdx.x*256+threadIdx.x;        // 256K int4 groups
  int b = bbase[gid>>8];                        // (gid*4)>>10
  int4 v = *(int4*)(off + gid*4);
  v.x+=b; v.y+=b; v.z+=b; v.w+=b;
  *(int4*)(off + gid*4)=v;
}

// ---------------------------------------------------------------- reorder into CSR
// After this kernel, off[b] = END of bin b (start = off[b-1], off[-1]=0).
__global__ __launch_bounds__(256) void k_reorder(const float* kt, const float* kre, const float* kim,
                                                 int* off, float2* stat, int* cellArr,
                                                 float2* ysub, float2* kdat, const float* t){
  int m = blockIdx.x*256+threadIdx.x;
  if (m>=M_) return;
  float kx=kt[2*m], ky=kt[2*m+1];
  float gx=kx*1024.f, gy=ky*1024.f;
  float fx=floorf(gx), fy=floorf(gy);
  float tx=gx-fx, ty=gy-fy;
  int ix=((int)fx)&1023, iy=((int)fy)&1023;
  int cellv=(ix<<10)|iy;
  int pos = atomicAdd(&off[cellv],1);
  stat[pos]=make_float2(tx,ty);
  cellArr[pos]=cellv;
  float dx=kx-0.5f, dy=ky-0.5f;
  float r=sqrtf(dx*dx+dy*dy);
  float dcf=sqrtf(r/(t[15]+1e-8f));
  ysub[pos]=make_float2(kre[m]*dcf, kim[m]*dcf);
  // av0 = gather(fft2(ones)) contribution: weights whose target cell is (0,0)
  int idx[4]; float w[4];
  corners(kx,ky,idx,w);
  float s=0.f;
#pragma unroll
  for(int q=0;q<4;q++) if (idx[q]==0) s+=w[q];
  kdat[pos]=make_float2(1024.f*s,0.f);
}

// ---------------------------------------------------------------- adjoint: grid-side gather (atomic-free)
// G[cell] = sc * sum over 4 bins of weighted kdat
__global__ __launch_bounds__(256) void k_adj(const float2* __restrict__ stat,
                                             const float2* __restrict__ kdat,
                                             const int* __restrict__ off,
                                             float2* __restrict__ G,
                                             const float* __restrict__ t, int chain_n){
  int gid = blockIdx.x*256+threadIdx.x;
  int r = gid>>10, c = gid&1023;
  float sc = 1.f;
  if (chain_n>0) sc = 1.f/(sqrtf(chain_t(t,chain_n-1))+1e-12f);
  float sx=0.f, sy=0.f;
#pragma unroll
  for(int dr=0;dr<2;dr++){
    int br=(r-dr)&1023;
    int rowbase = br<<10;
    if (c>0){
      int bL = rowbase|(c-1);
      int s0 = (bL==0)?0:off[bL-1];
      int mid = off[bL];
      int s1 = off[bL+1];
      for(int j=s0;j<s1;j++){
        float2 st=stat[j]; float2 v=kdat[j];
        float wxx = dr? st.x : 1.f-st.x;
        float wyy = (j<mid)? st.y : 1.f-st.y;
        float wt = wxx*wyy;
        sx=fmaf(wt,v.x,sx); sy=fmaf(wt,v.y,sy);
      }
    } else {
      int bA = rowbase|1023;                 // bin col 1023 (dc=1)
      int a0 = off[bA-1], a1 = off[bA];
      for(int j=a0;j<a1;j++){
        float2 st=stat[j]; float2 v=kdat[j];
        float wt = (dr? st.x : 1.f-st.x) * st.y;
        sx=fmaf(wt,v.x,sx); sy=fmaf(wt,v.y,sy);
      }
      int bB = rowbase;                      // bin col 0 (dc=0)
      int b0 = (bB==0)?0:off[bB-1], b1 = off[bB];
      for(int j=b0;j<b1;j++){
        float2 st=stat[j]; float2 v=kdat[j];
        float wt = (dr? st.x : 1.f-st.x) * (1.f-st.y);
        sx=fmaf(wt,v.x,sx); sy=fmaf(wt,v.y,sy);
      }
    }
  }
  G[gid]=make_float2(sx*sc, sy*sc);
}

// ---------------------------------------------------------------- forward gather (sorted order)
__device__ __forceinline__ void fwd_point(const float2* __restrict__ G, int cellv, float2 st,
                                          float& sx, float& sy){
  int ix=cellv>>10, iy=cellv&1023;
  int ix1=(ix+1)&1023, iy1=(iy+1)&1023;
  float tx=st.x, ty=st.y, ux=1.f-tx, uy=1.f-ty;
  float2 g00=G[(ix<<10)|iy], g10=G[(ix1<<10)|iy], g01=G[(ix<<10)|iy1], g11=G[(ix1<<10)|iy1];
  float w0=ux*uy, w1=tx*uy, w2=ux*ty, w3=tx*ty;
  sx = fmaf(w0,g00.x,fmaf(w1,g10.x,fmaf(w2,g01.x,w3*g11.x)));
  sy = fmaf(w0,g00.y,fmaf(w1,g10.y,fmaf(w2,g01.y,w3*g11.y)));
}

// power-iteration gather: kdat <- gather(G); dot_n -> t[n]; if last also ssq -> t[10]
__global__ __launch_bounds__(256) void k_fwd_pow(const float2* __restrict__ G,
                                                 const int* __restrict__ cellArr,
                                                 const float2* __restrict__ stat,
                                                 float2* kdat, float* t, int n, int last){
  int j = blockIdx.x*256+threadIdx.x;
  float dot=0.f, ssq=0.f;
  if (j<M_){
    float sx,sy;
    fwd_point(G,cellArr[j],stat[j],sx,sy);
    float2 old = kdat[j];
    dot = sx*old.x + sy*old.y;
    ssq = sx*sx + sy*sy;
    kdat[j]=make_float2(sx,sy);
  }
  __shared__ float sm[4];
  for(int o=32;o>0;o>>=1) dot += __shfl_down(dot,o,64);
  if((threadIdx.x&63)==0) sm[threadIdx.x>>6]=dot;
  __syncthreads();
  if(threadIdx.x==0) atomicAdd(t+n, sm[0]+sm[1]+sm[2]+sm[3]);
  if (last){
    __syncthreads();
    for(int o=32;o>0;o>>=1) ssq += __shfl_down(ssq,o,64);
    if((threadIdx.x&63)==0) sm[threadIdx.x>>6]=ssq;
    __syncthreads();
    if(threadIdx.x==0) atomicAdd(t+10, sm[0]+sm[1]+sm[2]+sm[3]);
  }
}

// npcg gather: kdat <- gather(G) - y*dcf (precomputed ysub)
__global__ __launch_bounds__(256) void k_fwd_sub(const float2* __restrict__ G,
                                                 const int* __restrict__ cellArr,
                                                 const float2* __restrict__ stat,
                                                 const float2* __restrict__ ysub,
                                                 float2* kdat){
  int j = blockIdx.x*256+threadIdx.x;
  if (j>=M_) return;
  float sx,sy;
  fwd_point(G,cellArr[j],stat[j],sx,sy);
  float2 yv = ysub[j];
  kdat[j]=make_float2(sx-yv.x, sy-yv.y);
}

// ---------------------------------------------------------------- fused CNN + update
#define XT_S 76
#define XT_P (70*76)
__global__ __launch_bounds__(256) void k_cnn(const float2* __restrict__ x, const float2* __restrict__ res,
    const float* __restrict__ w1, const float* __restrict__ b1,
    const float* __restrict__ w2, const float* __restrict__ b2,
    const float* __restrict__ wraw, const float* __restrict__ t, float2* __restrict__ xout){
  __shared__ __align__(16) float xt[2*XT_P];
  __shared__ __align__(16) float ht[68*XT_S];
  int tid = threadIdx.x;
  int ty0 = (blockIdx.x>>4)<<6, tx0 = (blockIdx.x&15)<<6;

  for (int p=tid; p<70*70; p+=256){
    int r=p/70, c=p-r*70;
    int gy=ty0-2+r, gx=tx0-2+c;
    float vx=0.f, vy=0.f;
    if ((unsigned)gy<1024u && (unsigned)gx<1024u){
      float2 v = x[(size_t)gy*W_+gx]; vx=v.x; vy=v.y;
    }
    xt[r*XT_S+c]=vx; xt[XT_P + r*XT_S+c]=vy;
  }
  float acc0[16], acc1[16];
#pragma unroll
  for(int q=0;q<16;q++){ acc0[q]=0.f; acc1[q]=0.f; }
  int oby = tid>>4, obx = tid&15;
  __syncthreads();

  for (int cm=0; cm<32; cm++){
    const float* W1 = w1 + cm*18;
    float b1v = b1[cm];
    for (int b=tid; b<289; b+=256){
      int by=b/17, bx=b-by*17;
      float h[4][4];
#pragma unroll
      for(int i=0;i<4;i++)
#pragma unroll
        for(int j=0;j<4;j++) h[i][j]=b1v;
#pragma unroll
      for (int l=0;l<6;l++){
        int rw = 4*by+l;
        const float* p0 = &xt[rw*XT_S + 4*bx];
        const float* p1 = p0 + XT_P;
        float4 a0 = *(const float4*)p0; float2 a1 = *(const float2*)(p0+4);
        float4 c0 = *(const float4*)p1; float2 c1 = *(const float2*)(p1+4);
        float f0[6]={a0.x,a0.y,a0.z,a0.w,a1.x,a1.y};
        float f1[6]={c0.x,c0.y,c0.z,c0.w,c1.x,c1.y};
#pragma unroll
        for(int i=0;i<4;i++){
          int dy = l-i;
          if (dy<0||dy>2) continue;
#pragma unroll
          for(int j=0;j<4;j++){
            float s=h[i][j];
#pragma unroll
            for(int dx=0;dx<3;dx++){
              s = fmaf(W1[dy*3+dx],   f0[j+dx], s);
              s = fmaf(W1[9+dy*3+dx], f1[j+dx], s);
            }
            h[i][j]=s;
          }
        }
      }
#pragma unroll
      for(int i=0;i<4;i++){
        int gy = ty0 + 4*by-1+i;
#pragma unroll
        for(int j=0;j<4;j++){
          int gx = tx0 + 4*bx-1+j;
          if ((unsigned)gy>=1024u || (unsigned)gx>=1024u) h[i][j]=0.f;
        }
        *(float4*)&ht[(4*by+i)*XT_S + 4*bx] = make_float4(h[i][0],h[i][1],h[i][2],h[i][3]);
      }
    }
    __syncthreads();
    const float* W2a = w2 + cm*9;
    const float* W2b = w2 + (32+cm)*9;
#pragma unroll
    for (int l=0;l<6;l++){
      const float* p = &ht[(4*oby+l)*XT_S + 4*obx];
      float4 a=*(const float4*)p; float2 bb=*(const float2*)(p+4);
      float f[6]={a.x,a.y,a.z,a.w,bb.x,bb.y};
#pragma unroll
      for(int i=0;i<4;i++){
        int ky = l-i;
        if (ky<0||ky>2) continue;
#pragma unroll
        for(int j=0;j<4;j++){
          float sA=0.f, sB=0.f;
#pragma unroll
          for(int kx=0;kx<3;kx++){
            sA = fmaf(W2a[ky*3+kx], f[j+kx], sA);
            sB = fmaf(W2b[ky*3+kx], f[j+kx], sB);
          }
          acc0[i*4+j]+=sA; acc1[i*4+j]+=sB;
        }
      }
    }
    __syncthreads();
  }

  float t8 = chain_t(t,8);
  float c9 = 1.f/(sqrtf(t8)+1e-12f);
  float avn = c9*sqrtf(t[10]);
  float vn  = sqrtf(t8)*c9;
  float opn = avn/(vn+1e-12f);
  float sig = 1.f/(1.f+__expf(-wraw[0]));
  float wreg = 2.f*sig/(opn*opn);
  float b20=b2[0], b21=b2[1];
#pragma unroll
  for(int i=0;i<4;i++){
    int oy=4*oby+i, gy=ty0+oy;
#pragma unroll
    for(int j=0;j<4;j++){
      int ox=4*obx+j, gx=tx0+ox;
      float xr_ = xt[(oy+2)*XT_S+ox+2];
      float xi_ = xt[XT_P + (oy+2)*XT_S+ox+2];
      float2 rv = res[(size_t)gy*W_+gx];
      float o0 = acc0[i*4+j]+b20;
      float o1 = acc1[i*4+j]+b21;
      xout[(size_t)gy*W_+gx] = make_float2(xr_ - wreg*rv.x - o0,
                                           xi_ - wreg*rv.y - o1);
    }
  }
}

__global__ __launch_bounds__(256) void k_unpack(const float2* X, float* out){
  int i = blockIdx.x*256+threadIdx.x;
  if (i<HW_){ out[i]=X[i].x; out[HW_+i]=X[i].y; }
}

// ================================================================ launch
extern "C" void kernel_launch(void* const* d_in, const int* in_sizes, int n_in,
                              void* d_out, int out_size, void* d_ws, size_t ws_size,
                              hipStream_t stream){
  (void)in_sizes; (void)n_in; (void)out_size; (void)ws_size;
  const float* xr  =(const float*)d_in[0];
  const float* xi  =(const float*)d_in[1];
  const float* kre =(const float*)d_in[2];
  const float* kim =(const float*)d_in[3];
  const float* kt  =(const float*)d_in[4];
  const float* wraw=(const float*)d_in[5];
  const float* w1  =(const float*)d_in[6];
  const float* b1  =(const float*)d_in[7];
  const float* w2  =(const float*)d_in[8];
  const float* b2  =(const float*)d_in[9];
  float* out = (float*)d_out;

  char* ws=(char*)d_ws;
  float2* Wx0 =(float2*)(ws);                      // 8MB
  float2* Wx1 =(float2*)(ws + ((size_t) 8<<20));   // 8MB (counts alias in setup)
  int*   counts=(int*)   (ws + ((size_t) 8<<20));  // 4MB, alias of Wx1 (setup only)
  float2* WF  =(float2*)(ws + ((size_t)16<<20));   // 8MB
  float2* kdat=(float2*)(ws + ((size_t)24<<20));   // 4MB
  float2* stat=(float2*)(ws + ((size_t)28<<20));   // 4MB (tx,ty sorted)
  float2* ysub=(float2*)(ws + ((size_t)32<<20));   // 4MB (y*dcf sorted)
  int*  cellA =(int*)   (ws + ((size_t)36<<20));   // 2MB
  int*  off   =(int*)   (ws + ((size_t)38<<20));   // 4MB
  int*  bsum  =(int*)   (ws + ((size_t)42<<20));   // 4KB
  float* t    =(float*) (ws + ((size_t)42<<20) + 8192);
  const float SC = 0.03125f;   // 1/32 per 1-D ortho pass

  // ---- setup: pack x, one-time counting sort of trajectory
  k_pack<<<HW_/256,256,0,stream>>>(xr,xi,Wx0,t);
  hipMemsetAsync(counts,0,(size_t)HW_*sizeof(int),stream);
  k_hist<<<M_/256,256,0,stream>>>(kt,counts,t);
  k_scan1<<<1024,256,0,stream>>>(counts,off,bsum);
  k_scan2<<<1,256,0,stream>>>(bsum);
  k_scan3<<<1024,256,0,stream>>>(off,bsum);
  k_reorder<<<M_/256,256,0,stream>>>(kt,kre,kim,off,stat,cellA,ysub,kdat,t);

  // ---- power iteration, fully in k-space (fft2/ifft2 cancel; Parseval for norms)
  for (int n=0;n<9;n++){
    k_adj<<<HW_/256,256,0,stream>>>(stat,kdat,off,WF,t,n);
    k_fwd_pow<<<M_/256,256,0,stream>>>(WF,cellA,stat,kdat,t,n,(n==8)?1:0);
  }

  // ---- npcg = 4 PGD iterations
  for (int it=0; it<4; it++){
    float2* xin  = (it&1)? Wx1 : Wx0;
    float2* xout = (it&1)? Wx0 : Wx1;
    k_fft_rows<-1><<<H_,256,0,stream>>>(xin,WF,SC);
    k_fft_cols<-1><<<W_/4,256,0,stream>>>(WF,SC);
    k_fwd_sub<<<M_/256,256,0,stream>>>(WF,cellA,stat,ysub,kdat);
    k_adj<<<HW_/256,256,0,stream>>>(stat,kdat,off,WF,t,-1);
    k_fft_rows<1><<<H_,256,0,stream>>>(WF,WF,SC);
    k_fft_cols<1><<<W_/4,256,0,stream>>>(WF,SC);
    k_cnn<<<256,256,0,stream>>>(xin,WF,w1,b1,w2,b2,wraw,t,xout);
  }
  k_unpack<<<HW_/256,256,0,stream>>>(Wx0,out);
}

// Round 3
// 1065.087 us; speedup vs baseline: 3.6957x; 1.2538x over previous
//
#include <hip/hip_runtime.h>

#define H_  1024
#define W_  1024
#define HW_ (H_*W_)
#define M_  524288

#define SWZ(a) ((a) + ((a)>>4))

// ---------------------------------------------------------------- complex mul
__device__ __forceinline__ float2 cmulf(float2 a, float2 b){
  return make_float2(fmaf(a.x,b.x,-(a.y*b.y)), fmaf(a.x,b.y,a.y*b.x));
}

// ---------------------------------------------------------------- radix-4 bfly
template<int DIR>
__device__ __forceinline__ void bfly4(float2 v[4], int j, int Ns){
  if (Ns>1){
    float ang = ((DIR>0)?6.28318530717958647692f:-6.28318530717958647692f)
                * (float)(j&(Ns-1)) / (float)(4*Ns);
    float s,c; __sincosf(ang,&s,&c);
    float2 w1=make_float2(c,s);
    float2 w2=cmulf(w1,w1);
    float2 w3=cmulf(w2,w1);
    v[1]=cmulf(v[1],w1); v[2]=cmulf(v[2],w2); v[3]=cmulf(v[3],w3);
  }
  float2 t0=make_float2(v[0].x+v[2].x, v[0].y+v[2].y);
  float2 t2=make_float2(v[0].x-v[2].x, v[0].y-v[2].y);
  float2 t1=make_float2(v[1].x+v[3].x, v[1].y+v[3].y);
  float2 t3=make_float2(v[1].x-v[3].x, v[1].y-v[3].y);
  float2 t3r=(DIR<0)?make_float2(t3.y,-t3.x):make_float2(-t3.y,t3.x);
  v[0]=make_float2(t0.x+t1.x,  t0.y+t1.y);
  v[1]=make_float2(t2.x+t3r.x, t2.y+t3r.y);
  v[2]=make_float2(t0.x-t1.x,  t0.y-t1.y);
  v[3]=make_float2(t2.x-t3r.x, t2.y-t3r.y);
}

template<int DIR, int NS>
__device__ __forceinline__ void fft_stage(int j, const float2* src, float2* dst){
  float2 v[4];
#pragma unroll
  for(int r=0;r<4;r++) v[r]=src[SWZ(j+256*r)];
  bfly4<DIR>(v,j,NS);
  int base = ((j & ~(NS-1))<<2) | (j&(NS-1));
#pragma unroll
  for(int r=0;r<4;r++) dst[SWZ(base+NS*r)]=v[r];
}

template<int DIR>
__device__ __forceinline__ void fft1024_core(float2 v[4], int j, float2* A, float2* B, float scale){
  bfly4<DIR>(v,j,1);
#pragma unroll
  for(int r=0;r<4;r++) A[SWZ(4*j+r)]=v[r];
  __syncthreads();
  fft_stage<DIR,4 >(j,A,B); __syncthreads();
  fft_stage<DIR,16>(j,B,A); __syncthreads();
  fft_stage<DIR,64>(j,A,B); __syncthreads();
#pragma unroll
  for(int r=0;r<4;r++) v[r]=B[SWZ(j+256*r)];
  bfly4<DIR>(v,j,256);
#pragma unroll
  for(int r=0;r<4;r++){ v[r].x*=scale; v[r].y*=scale; }
}

template<int DIR>
__global__ __launch_bounds__(256) void k_fft_rows(const float2* src, float2* dst, float scale){
  __shared__ float2 A[1088], B[1088];
  int j = threadIdx.x;
  const float2* s = src + (size_t)blockIdx.x*W_;
  float2 v[4];
#pragma unroll
  for(int r=0;r<4;r++) v[r]=s[j+256*r];
  fft1024_core<DIR>(v,j,A,B,scale);
  float2* d = dst + (size_t)blockIdx.x*W_;
#pragma unroll
  for(int r=0;r<4;r++) d[j+256*r]=v[r];
}

template<int DIR>
__global__ __launch_bounds__(256) void k_fft_cols(float2* data, float scale){
  __shared__ float2 T[4*1025];
  __shared__ float2 A[1088], B[1088];
  int tid=threadIdx.x, c0=blockIdx.x*4;
#pragma unroll
  for(int k=0;k<16;k++){
    int idx=tid+256*k; int c=idx&3, r=idx>>2;
    T[c*1025+r]=data[(size_t)r*W_ + c0 + c];
  }
  __syncthreads();
  for(int c=0;c<4;c++){
    float2* col = T + c*1025;
    float2 v[4];
#pragma unroll
    for(int r=0;r<4;r++) v[r]=col[tid+256*r];
    fft1024_core<DIR>(v,tid,A,B,scale);
#pragma unroll
    for(int r=0;r<4;r++) col[tid+256*r]=v[r];
  }
  __syncthreads();
#pragma unroll
  for(int k=0;k<16;k++){
    int idx=tid+256*k; int c=idx&3, r=idx>>2;
    data[(size_t)r*W_ + c0 + c]=T[c*1025+r];
  }
}

// ---------------------------------------------------------------- interp helpers
__device__ __forceinline__ void corners(float kx, float ky, int idx[4], float w[4]){
  float gx = kx*1024.f, gy = ky*1024.f;
  float fx = floorf(gx), fy = floorf(gy);
  float tx = gx-fx, ty = gy-fy;
  int ix = ((int)fx)&1023, iy = ((int)fy)&1023;
  int ix1=(ix+1)&1023, iy1=(iy+1)&1023;
  idx[0]=(ix<<10)|iy;  idx[1]=(ix1<<10)|iy;
  idx[2]=(ix<<10)|iy1; idx[3]=(ix1<<10)|iy1;
  float ux=1.f-tx, uy=1.f-ty;
  w[0]=ux*uy; w[1]=tx*uy; w[2]=ux*ty; w[3]=tx*ty;
}

// chain: t_0 = dot_0 ; t_n = dot_n/(sqrt(t_{n-1})+1e-12)
__device__ __forceinline__ float chain_t(const float* t, int n){
  float tv = t[0];
  for(int k=1;k<=n;k++) tv = t[k]/(sqrtf(tv)+1e-12f);
  return tv;
}

// ---------------------------------------------------------------- init
__global__ __launch_bounds__(256) void k_pack(const float* xr, const float* xi, float2* X, float* t){
  int i = blockIdx.x*256+threadIdx.x;
  if (i<HW_) X[i]=make_float2(xr[i],xi[i]);
  if (blockIdx.x==0 && threadIdx.x<16) t[threadIdx.x]=0.f;
}

// histogram by base cell + max radius
__global__ __launch_bounds__(256) void k_hist(const float* kt, int* counts, float* t){
  int m = blockIdx.x*256+threadIdx.x;
  float r = 0.f;
  if (m < M_){
    float kx=kt[2*m], ky=kt[2*m+1];
    float dx=kx-0.5f, dy=ky-0.5f;
    r = sqrtf(dx*dx+dy*dy);
    int ix = ((int)floorf(kx*1024.f))&1023;
    int iy = ((int)floorf(ky*1024.f))&1023;
    atomicAdd(&counts[(ix<<10)|iy],1);
  }
  for(int o=32;o>0;o>>=1) r = fmaxf(r, __shfl_down(r,o,64));
  __shared__ float sm[4];
  if((threadIdx.x&63)==0) sm[threadIdx.x>>6]=r;
  __syncthreads();
  if(threadIdx.x==0){
    r = fmaxf(fmaxf(sm[0],sm[1]),fmaxf(sm[2],sm[3]));
    atomicMax((int*)(t+15), __float_as_int(r));
  }
}

// ---------------------------------------------------------------- scan (1M = 1024 blocks x 1024)
__global__ __launch_bounds__(256) void k_scan1(const int* cnt, int* off, int* bsum){
  __shared__ int sm[256];
  int base = blockIdx.x*1024;
  int tid = threadIdx.x;
  int4 c = *(const int4*)(cnt + base + tid*4);
  int s = c.x+c.y+c.z+c.w;
  sm[tid]=s; __syncthreads();
  int v=s;
  for(int o=1;o<256;o<<=1){
    int u = (tid>=o)? sm[tid-o]:0;
    __syncthreads();
    v += u; sm[tid]=v;
    __syncthreads();
  }
  int excl = v - s;
  int4 o4;
  o4.x=excl; o4.y=excl+c.x; o4.z=excl+c.x+c.y; o4.w=excl+c.x+c.y+c.z;
  *(int4*)(off+base+tid*4)=o4;
  if (tid==255) bsum[blockIdx.x]=v;
}

__global__ __launch_bounds__(256) void k_scan2(int* bsum){
  __shared__ int sm[256];
  int tid=threadIdx.x;
  int4 c = *(const int4*)(bsum + tid*4);
  int s = c.x+c.y+c.z+c.w;
  sm[tid]=s; __syncthreads();
  int v=s;
  for(int o=1;o<256;o<<=1){
    int u = (tid>=o)? sm[tid-o]:0;
    __syncthreads();
    v += u; sm[tid]=v;
    __syncthreads();
  }
  int excl=v-s;
  int4 o4;
  o4.x=excl; o4.y=excl+c.x; o4.z=excl+c.x+c.y; o4.w=excl+c.x+c.y+c.z;
  *(int4*)(bsum+tid*4)=o4;
}

__global__ __launch_bounds__(256) void k_scan3(int* off, const int* bbase){
  int gid = blockIdx.x*256+threadIdx.x;
  int b = bbase[gid>>8];
  int4 v = *(int4*)(off + gid*4);
  v.x+=b; v.y+=b; v.z+=b; v.w+=b;
  *(int4*)(off + gid*4)=v;
}

// ---------------------------------------------------------------- reorder into CSR
__global__ __launch_bounds__(256) void k_reorder(const float* kt, const float* kre, const float* kim,
                                                 int* off, float2* stat, int* cellArr,
                                                 float2* ysub, float2* kdat, const float* t){
  int m = blockIdx.x*256+threadIdx.x;
  if (m>=M_) return;
  float kx=kt[2*m], ky=kt[2*m+1];
  float gx=kx*1024.f, gy=ky*1024.f;
  float fx=floorf(gx), fy=floorf(gy);
  float tx=gx-fx, ty=gy-fy;
  int ix=((int)fx)&1023, iy=((int)fy)&1023;
  int cellv=(ix<<10)|iy;
  int pos = atomicAdd(&off[cellv],1);
  stat[pos]=make_float2(tx,ty);
  cellArr[pos]=cellv;
  float dx=kx-0.5f, dy=ky-0.5f;
  float r=sqrtf(dx*dx+dy*dy);
  float dcf=sqrtf(r/(t[15]+1e-8f));
  ysub[pos]=make_float2(kre[m]*dcf, kim[m]*dcf);
  int idx[4]; float w[4];
  corners(kx,ky,idx,w);
  float s=0.f;
#pragma unroll
  for(int q=0;q<4;q++) if (idx[q]==0) s+=w[q];
  kdat[pos]=make_float2(1024.f*s,0.f);
}

// ---------------------------------------------------------------- adjoint: grid-side gather (atomic-free)
__global__ __launch_bounds__(256) void k_adj(const float2* __restrict__ stat,
                                             const float2* __restrict__ kdat,
                                             const int* __restrict__ off,
                                             float2* __restrict__ G,
                                             const float* __restrict__ t, int chain_n){
  int gid = blockIdx.x*256+threadIdx.x;
  int r = gid>>10, c = gid&1023;
  float sc = 1.f;
  if (chain_n>0) sc = 1.f/(sqrtf(chain_t(t,chain_n-1))+1e-12f);
  float sx=0.f, sy=0.f;
#pragma unroll
  for(int dr=0;dr<2;dr++){
    int br=(r-dr)&1023;
    int rowbase = br<<10;
    if (c>0){
      int bL = rowbase|(c-1);
      int s0 = (bL==0)?0:off[bL-1];
      int mid = off[bL];
      int s1 = off[bL+1];
      for(int j=s0;j<s1;j++){
        float2 st=stat[j]; float2 v=kdat[j];
        float wxx = dr? st.x : 1.f-st.x;
        float wyy = (j<mid)? st.y : 1.f-st.y;
        float wt = wxx*wyy;
        sx=fmaf(wt,v.x,sx); sy=fmaf(wt,v.y,sy);
      }
    } else {
      int bA = rowbase|1023;
      int a0 = off[bA-1], a1 = off[bA];
      for(int j=a0;j<a1;j++){
        float2 st=stat[j]; float2 v=kdat[j];
        float wt = (dr? st.x : 1.f-st.x) * st.y;
        sx=fmaf(wt,v.x,sx); sy=fmaf(wt,v.y,sy);
      }
      int bB = rowbase;
      int b0 = (bB==0)?0:off[bB-1], b1 = off[bB];
      for(int j=b0;j<b1;j++){
        float2 st=stat[j]; float2 v=kdat[j];
        float wt = (dr? st.x : 1.f-st.x) * (1.f-st.y);
        sx=fmaf(wt,v.x,sx); sy=fmaf(wt,v.y,sy);
      }
    }
  }
  G[gid]=make_float2(sx*sc, sy*sc);
}

// ---------------------------------------------------------------- forward gather (sorted order)
__device__ __forceinline__ void fwd_point(const float2* __restrict__ G, int cellv, float2 st,
                                          float& sx, float& sy){
  int ix=cellv>>10, iy=cellv&1023;
  int ix1=(ix+1)&1023, iy1=(iy+1)&1023;
  float tx=st.x, ty=st.y, ux=1.f-tx, uy=1.f-ty;
  float2 g00=G[(ix<<10)|iy], g10=G[(ix1<<10)|iy], g01=G[(ix<<10)|iy1], g11=G[(ix1<<10)|iy1];
  float w0=ux*uy, w1=tx*uy, w2=ux*ty, w3=tx*ty;
  sx = fmaf(w0,g00.x,fmaf(w1,g10.x,fmaf(w2,g01.x,w3*g11.x)));
  sy = fmaf(w0,g00.y,fmaf(w1,g10.y,fmaf(w2,g01.y,w3*g11.y)));
}

__global__ __launch_bounds__(256) void k_fwd_pow(const float2* __restrict__ G,
                                                 const int* __restrict__ cellArr,
                                                 const float2* __restrict__ stat,
                                                 float2* kdat, float* t, int n, int last){
  int j = blockIdx.x*256+threadIdx.x;
  float dot=0.f, ssq=0.f;
  if (j<M_){
    float sx,sy;
    fwd_point(G,cellArr[j],stat[j],sx,sy);
    float2 old = kdat[j];
    dot = sx*old.x + sy*old.y;
    ssq = sx*sx + sy*sy;
    kdat[j]=make_float2(sx,sy);
  }
  __shared__ float sm[4];
  for(int o=32;o>0;o>>=1) dot += __shfl_down(dot,o,64);
  if((threadIdx.x&63)==0) sm[threadIdx.x>>6]=dot;
  __syncthreads();
  if(threadIdx.x==0) atomicAdd(t+n, sm[0]+sm[1]+sm[2]+sm[3]);
  if (last){
    __syncthreads();
    for(int o=32;o>0;o>>=1) ssq += __shfl_down(ssq,o,64);
    if((threadIdx.x&63)==0) sm[threadIdx.x>>6]=ssq;
    __syncthreads();
    if(threadIdx.x==0) atomicAdd(t+10, sm[0]+sm[1]+sm[2]+sm[3]);
  }
}

__global__ __launch_bounds__(256) void k_fwd_sub(const float2* __restrict__ G,
                                                 const int* __restrict__ cellArr,
                                                 const float2* __restrict__ stat,
                                                 const float2* __restrict__ ysub,
                                                 float2* kdat){
  int j = blockIdx.x*256+threadIdx.x;
  if (j>=M_) return;
  float sx,sy;
  fwd_point(G,cellArr[j],stat[j],sx,sy);
  float2 yv = ysub[j];
  kdat[j]=make_float2(sx-yv.x, sy-yv.y);
}

// ---------------------------------------------------------------- composed-conv tables
// ec layout (floats): [0..99] E[oc*50+ic*25+dy*5+dx]; [100..101] C0;
// [102..119] Bb[oc*9+u]; [120..443] Btab[oc*162+u*18+ic*9+v]; [444..445] b2
__global__ __launch_bounds__(256) void k_mkE(const float* w1, const float* b1,
                                             const float* w2, const float* b2, float* ec){
  __shared__ float sw1[576], sw2[576], sb1[32], sB[324];
  int tid=threadIdx.x;
  for(int p=tid;p<576;p+=256){ sw1[p]=w1[p]; sw2[p]=w2[p]; }
  if(tid<32) sb1[tid]=b1[tid];
  __syncthreads();
  for(int e=tid;e<324;e+=256){
    int oc=e/162, r=e-oc*162, u=r/18, r2=r-u*18, ic=r2/9, v=r2-ic*9;
    float s=0.f;
    for(int cm=0;cm<32;cm++) s=fmaf(sw2[oc*288+cm*9+u], sw1[cm*18+ic*9+v], s);
    sB[e]=s; ec[120+e]=s;
  }
  if(tid<18){
    int oc=tid/9, u=tid-oc*9;
    float s=0.f;
    for(int cm=0;cm<32;cm++) s=fmaf(sw2[oc*288+cm*9+u], sb1[cm], s);
    ec[102+tid]=s;
  }
  if(tid<2){
    float s=b2[tid];
    for(int u=0;u<9;u++){
      float bb=0.f;
      for(int cm=0;cm<32;cm++) bb=fmaf(sw2[tid*288+cm*9+u], sb1[cm], bb);
      s+=bb;
    }
    ec[100+tid]=s;
    ec[444+tid]=b2[tid];
  }
  __syncthreads();
  if(tid<100){
    int oc=tid/50, r=tid-oc*50, ic=r/25, r2=r-ic*25, dy=r2/5, dx=r2-dy*5;
    float s=0.f;
    for(int uy=0;uy<3;uy++){ int vy=dy-uy; if(vy<0||vy>2) continue;
      for(int ux=0;ux<3;ux++){ int vx=dx-ux; if(vx<0||vx>2) continue;
        s+=sB[oc*162+(uy*3+ux)*18+ic*9+vy*3+vx];
      }
    }
    ec[tid]=s;
  }
}

// ---------------------------------------------------------------- fused 5x5 composed CNN + update
#define CT_S 40
__global__ __launch_bounds__(256) void k_cnn5(const float2* __restrict__ x, const float2* __restrict__ res,
    const float* __restrict__ ec, const float* __restrict__ wraw, const float* __restrict__ t,
    float2* __restrict__ xout, float* __restrict__ outPlanar){
  __shared__ __align__(16) float xt0[36*CT_S];
  __shared__ __align__(16) float xt1[36*CT_S];
  __shared__ float sE[446];
  int tid=threadIdx.x;
  int by=blockIdx.x>>5, bx=blockIdx.x&31;
  int ty0=by<<5, tx0=bx<<5;
  for(int p=tid;p<446;p+=256) sE[p]=ec[p];
  for(int p=tid;p<1296;p+=256){
    int r=p/36, c=p-r*36;
    int gy=ty0-2+r, gx=tx0-2+c;
    float vx=0.f, vy=0.f;
    if((unsigned)gy<1024u && (unsigned)gx<1024u){ float2 v=x[(size_t)gy*W_+gx]; vx=v.x; vy=v.y; }
    xt0[r*CT_S+c]=vx; xt1[r*CT_S+c]=vy;
  }
  __syncthreads();
  int row=tid>>3, c4=(tid&7)<<2;
  float a0[4], a1[4];
  float C00=sE[100], C01=sE[101];
#pragma unroll
  for(int jj=0;jj<4;jj++){ a0[jj]=C00; a1[jj]=C01; }
#pragma unroll
  for(int dy=0;dy<5;dy++){
    const float* r0=&xt0[(row+dy)*CT_S+c4];
    const float* r1=&xt1[(row+dy)*CT_S+c4];
    float f0[9], f1[9];
#pragma unroll
    for(int q=0;q<9;q++){ f0[q]=r0[q]; f1[q]=r1[q]; }
#pragma unroll
    for(int dx=0;dx<5;dx++){
      float e00=sE[dy*5+dx], e01=sE[25+dy*5+dx];
      float e10=sE[50+dy*5+dx], e11=sE[75+dy*5+dx];
#pragma unroll
      for(int jj=0;jj<4;jj++){
        a0[jj]=fmaf(e00,f0[jj+dx],fmaf(e01,f1[jj+dx],a0[jj]));
        a1[jj]=fmaf(e10,f0[jj+dx],fmaf(e11,f1[jj+dx],a1[jj]));
      }
    }
  }
  int py=ty0+row;
  // exact border ring: conv2 sees h=0 outside image, not the composed extension
  bool rowEdge = (py==0)||(py==1023);
  if (rowEdge || (tx0+c4)==0 || (tx0+c4+3)==1023){
    for(int jj=0;jj<4;jj++){
      int px=tx0+c4+jj;
      if(!(rowEdge || px==0 || px==1023)) continue;
      float s0=sE[444], s1=sE[445];
      for(int uy=0;uy<3;uy++){
        int qy=py+uy-1; if((unsigned)qy>=1024u) continue;
        for(int ux=0;ux<3;ux++){
          int qx=px+ux-1; if((unsigned)qx>=1024u) continue;
          int u=uy*3+ux;
          s0+=sE[102+u]; s1+=sE[111+u];
          const float* B0=&sE[120+u*18];
          const float* B1=&sE[282+u*18];
          for(int vy=0;vy<3;vy++){
            for(int vx=0;vx<3;vx++){
              int v=vy*3+vx;
              float xv0=xt0[(row+uy+vy)*CT_S + c4+jj+ux+vx];
              float xv1=xt1[(row+uy+vy)*CT_S + c4+jj+ux+vx];
              s0 = fmaf(B0[v],xv0,fmaf(B0[9+v],xv1,s0));
              s1 = fmaf(B1[v],xv0,fmaf(B1[9+v],xv1,s1));
            }
          }
        }
      }
      a0[jj]=s0; a1[jj]=s1;
    }
  }
  // epilogue: x - w_reg*res - xnn
  float t8 = chain_t(t,8);
  float c9 = 1.f/(sqrtf(t8)+1e-12f);
  float avn = c9*sqrtf(t[10]);
  float vn  = sqrtf(t8)*c9;
  float opn = avn/(vn+1e-12f);
  float sig = 1.f/(1.f+__expf(-wraw[0]));
  float wreg = 2.f*sig/(opn*opn);
  size_t base=(size_t)py*W_ + tx0 + c4;
  if (outPlanar){
#pragma unroll
    for(int jj=0;jj<4;jj++){
      float2 rv=res[base+jj];
      float xr_=xt0[(row+2)*CT_S+c4+jj+2];
      float xi_=xt1[(row+2)*CT_S+c4+jj+2];
      outPlanar[base+jj]      = xr_ - wreg*rv.x - a0[jj];
      outPlanar[HW_+base+jj]  = xi_ - wreg*rv.y - a1[jj];
    }
  } else {
#pragma unroll
    for(int jj=0;jj<4;jj++){
      float2 rv=res[base+jj];
      float xr_=xt0[(row+2)*CT_S+c4+jj+2];
      float xi_=xt1[(row+2)*CT_S+c4+jj+2];
      xout[base+jj]=make_float2(xr_ - wreg*rv.x - a0[jj],
                                xi_ - wreg*rv.y - a1[jj]);
    }
  }
}

// ================================================================ launch
extern "C" void kernel_launch(void* const* d_in, const int* in_sizes, int n_in,
                              void* d_out, int out_size, void* d_ws, size_t ws_size,
                              hipStream_t stream){
  (void)in_sizes; (void)n_in; (void)out_size; (void)ws_size;
  const float* xr  =(const float*)d_in[0];
  const float* xi  =(const float*)d_in[1];
  const float* kre =(const float*)d_in[2];
  const float* kim =(const float*)d_in[3];
  const float* kt  =(const float*)d_in[4];
  const float* wraw=(const float*)d_in[5];
  const float* w1  =(const float*)d_in[6];
  const float* b1  =(const float*)d_in[7];
  const float* w2  =(const float*)d_in[8];
  const float* b2  =(const float*)d_in[9];
  float* out = (float*)d_out;

  char* ws=(char*)d_ws;
  float2* Wx0 =(float2*)(ws);                      // 8MB
  float2* Wx1 =(float2*)(ws + ((size_t) 8<<20));   // 8MB (counts alias in setup)
  int*   counts=(int*)   (ws + ((size_t) 8<<20));  // 4MB alias (setup only)
  float2* WF  =(float2*)(ws + ((size_t)16<<20));   // 8MB
  float2* kdat=(float2*)(ws + ((size_t)24<<20));   // 4MB
  float2* stat=(float2*)(ws + ((size_t)28<<20));   // 4MB
  float2* ysub=(float2*)(ws + ((size_t)32<<20));   // 4MB
  int*  cellA =(int*)   (ws + ((size_t)36<<20));   // 2MB
  int*  off   =(int*)   (ws + ((size_t)38<<20));   // 4MB
  int*  bsum  =(int*)   (ws + ((size_t)42<<20));   // 4KB
  float* t    =(float*) (ws + ((size_t)42<<20) + 8192);
  float* ec   =(float*) (ws + ((size_t)42<<20) + 16384);
  const float SC = 0.03125f;   // 1/32 per 1-D ortho pass

  // ---- setup
  k_pack<<<HW_/256,256,0,stream>>>(xr,xi,Wx0,t);
  k_mkE<<<1,256,0,stream>>>(w1,b1,w2,b2,ec);
  hipMemsetAsync(counts,0,(size_t)HW_*sizeof(int),stream);
  k_hist<<<M_/256,256,0,stream>>>(kt,counts,t);
  k_scan1<<<1024,256,0,stream>>>(counts,off,bsum);
  k_scan2<<<1,256,0,stream>>>(bsum);
  k_scan3<<<1024,256,0,stream>>>(off,bsum);
  k_reorder<<<M_/256,256,0,stream>>>(kt,kre,kim,off,stat,cellA,ysub,kdat,t);

  // ---- power iteration, fully in k-space
  for (int n=0;n<9;n++){
    k_adj<<<HW_/256,256,0,stream>>>(stat,kdat,off,WF,t,n);
    k_fwd_pow<<<M_/256,256,0,stream>>>(WF,cellA,stat,kdat,t,n,(n==8)?1:0);
  }

  // ---- npcg = 4 PGD iterations
  for (int it=0; it<4; it++){
    float2* xin  = (it&1)? Wx1 : Wx0;
    float2* xout = (it&1)? Wx0 : Wx1;
    k_fft_rows<-1><<<H_,256,0,stream>>>(xin,WF,SC);
    k_fft_cols<-1><<<W_/4,256,0,stream>>>(WF,SC);
    k_fwd_sub<<<M_/256,256,0,stream>>>(WF,cellA,stat,ysub,kdat);
    k_adj<<<HW_/256,256,0,stream>>>(stat,kdat,off,WF,t,-1);
    k_fft_rows<1><<<H_,256,0,stream>>>(WF,WF,SC);
    k_fft_cols<1><<<W_/4,256,0,stream>>>(WF,SC);
    k_cnn5<<<1024,256,0,stream>>>(xin,WF,ec,wraw,t,xout,(it==3)? out : (float*)nullptr);
  }
}

// Round 4
// 843.343 us; speedup vs baseline: 4.6674x; 1.2629x over previous
//
#include <hip/hip_runtime.h>

#define H_  1024
#define W_  1024
#define HW_ (H_*W_)
#define M_  524288

#define SWZ(a) ((a) + ((a)>>4))

// ---------------------------------------------------------------- complex mul
__device__ __forceinline__ float2 cmulf(float2 a, float2 b){
  return make_float2(fmaf(a.x,b.x,-(a.y*b.y)), fmaf(a.x,b.y,a.y*b.x));
}

// ---------------------------------------------------------------- radix-4 bfly
template<int DIR>
__device__ __forceinline__ void bfly4(float2 v[4], int j, int Ns){
  if (Ns>1){
    float ang = ((DIR>0)?6.28318530717958647692f:-6.28318530717958647692f)
                * (float)(j&(Ns-1)) / (float)(4*Ns);
    float s,c; __sincosf(ang,&s,&c);
    float2 w1=make_float2(c,s);
    float2 w2=cmulf(w1,w1);
    float2 w3=cmulf(w2,w1);
    v[1]=cmulf(v[1],w1); v[2]=cmulf(v[2],w2); v[3]=cmulf(v[3],w3);
  }
  float2 t0=make_float2(v[0].x+v[2].x, v[0].y+v[2].y);
  float2 t2=make_float2(v[0].x-v[2].x, v[0].y-v[2].y);
  float2 t1=make_float2(v[1].x+v[3].x, v[1].y+v[3].y);
  float2 t3=make_float2(v[1].x-v[3].x, v[1].y-v[3].y);
  float2 t3r=(DIR<0)?make_float2(t3.y,-t3.x):make_float2(-t3.y,t3.x);
  v[0]=make_float2(t0.x+t1.x,  t0.y+t1.y);
  v[1]=make_float2(t2.x+t3r.x, t2.y+t3r.y);
  v[2]=make_float2(t0.x-t1.x,  t0.y-t1.y);
  v[3]=make_float2(t2.x-t3r.x, t2.y-t3r.y);
}

template<int DIR, int NS>
__device__ __forceinline__ void fft_stage(int j, const float2* src, float2* dst){
  float2 v[4];
#pragma unroll
  for(int r=0;r<4;r++) v[r]=src[SWZ(j+256*r)];
  bfly4<DIR>(v,j,NS);
  int base = ((j & ~(NS-1))<<2) | (j&(NS-1));
#pragma unroll
  for(int r=0;r<4;r++) dst[SWZ(base+NS*r)]=v[r];
}

template<int DIR>
__device__ __forceinline__ void fft1024_core(float2 v[4], int j, float2* A, float2* B, float scale){
  bfly4<DIR>(v,j,1);
#pragma unroll
  for(int r=0;r<4;r++) A[SWZ(4*j+r)]=v[r];
  __syncthreads();
  fft_stage<DIR,4 >(j,A,B); __syncthreads();
  fft_stage<DIR,16>(j,B,A); __syncthreads();
  fft_stage<DIR,64>(j,A,B); __syncthreads();
#pragma unroll
  for(int r=0;r<4;r++) v[r]=B[SWZ(j+256*r)];
  bfly4<DIR>(v,j,256);
#pragma unroll
  for(int r=0;r<4;r++){ v[r].x*=scale; v[r].y*=scale; }
}

template<int DIR>
__global__ __launch_bounds__(256) void k_fft_rows(const float2* src, float2* dst, float scale){
  __shared__ float2 A[1088], B[1088];
  int j = threadIdx.x;
  const float2* s = src + (size_t)blockIdx.x*W_;
  float2 v[4];
#pragma unroll
  for(int r=0;r<4;r++) v[r]=s[j+256*r];
  fft1024_core<DIR>(v,j,A,B,scale);
  float2* d = dst + (size_t)blockIdx.x*W_;
#pragma unroll
  for(int r=0;r<4;r++) d[j+256*r]=v[r];
}

template<int DIR>
__global__ __launch_bounds__(256) void k_fft_cols(float2* data, float scale){
  __shared__ float2 T[4*1025];
  __shared__ float2 A[1088], B[1088];
  int tid=threadIdx.x, c0=blockIdx.x*4;
#pragma unroll
  for(int k=0;k<16;k++){
    int idx=tid+256*k; int c=idx&3, r=idx>>2;
    T[c*1025+r]=data[(size_t)r*W_ + c0 + c];
  }
  __syncthreads();
  for(int c=0;c<4;c++){
    float2* col = T + c*1025;
    float2 v[4];
#pragma unroll
    for(int r=0;r<4;r++) v[r]=col[tid+256*r];
    fft1024_core<DIR>(v,tid,A,B,scale);
#pragma unroll
    for(int r=0;r<4;r++) col[tid+256*r]=v[r];
  }
  __syncthreads();
#pragma unroll
  for(int k=0;k<16;k++){
    int idx=tid+256*k; int c=idx&3, r=idx>>2;
    data[(size_t)r*W_ + c0 + c]=T[c*1025+r];
  }
}

// ---------------------------------------------------------------- interp helpers
__device__ __forceinline__ void corners(float kx, float ky, int idx[4], float w[4]){
  float gx = kx*1024.f, gy = ky*1024.f;
  float fx = floorf(gx), fy = floorf(gy);
  float tx = gx-fx, ty = gy-fy;
  int ix = ((int)fx)&1023, iy = ((int)fy)&1023;
  int ix1=(ix+1)&1023, iy1=(iy+1)&1023;
  idx[0]=(ix<<10)|iy;  idx[1]=(ix1<<10)|iy;
  idx[2]=(ix<<10)|iy1; idx[3]=(ix1<<10)|iy1;
  float ux=1.f-tx, uy=1.f-ty;
  w[0]=ux*uy; w[1]=tx*uy; w[2]=ux*ty; w[3]=tx*ty;
}

// ---------------------------------------------------------------- init
__global__ __launch_bounds__(256) void k_pack(const float* xr, const float* xi, float2* X, float* t){
  int i = blockIdx.x*256+threadIdx.x;
  if (i<HW_) X[i]=make_float2(xr[i],xi[i]);
  if (blockIdx.x==0 && threadIdx.x<32) t[threadIdx.x]=0.f;
}

// histogram by base cell + per-block max radius (plain store, no same-address atomics)
__global__ __launch_bounds__(256) void k_hist(const float* kt, int* counts, float* pmax){
  int m = blockIdx.x*256+threadIdx.x;
  float r = 0.f;
  {
    float kx=kt[2*m], ky=kt[2*m+1];
    float dx=kx-0.5f, dy=ky-0.5f;
    r = sqrtf(dx*dx+dy*dy);
    int ix = ((int)floorf(kx*1024.f))&1023;
    int iy = ((int)floorf(ky*1024.f))&1023;
    atomicAdd(&counts[(ix<<10)|iy],1);
  }
  for(int o=32;o>0;o>>=1) r = fmaxf(r, __shfl_down(r,o,64));
  __shared__ float sm[4];
  if((threadIdx.x&63)==0) sm[threadIdx.x>>6]=r;
  __syncthreads();
  if(threadIdx.x==0)
    pmax[blockIdx.x] = fmaxf(fmaxf(sm[0],sm[1]),fmaxf(sm[2],sm[3]));
}

__global__ __launch_bounds__(256) void k_reduce_max(const float* pmax, float* t){
  int tid=threadIdx.x;
  float s=-1e30f;
  for(int k=tid;k<2048;k+=256) s=fmaxf(s,pmax[k]);
  __shared__ float sm[4];
  for(int o=32;o>0;o>>=1) s=fmaxf(s,__shfl_down(s,o,64));
  if((tid&63)==0) sm[tid>>6]=s;
  __syncthreads();
  if(tid==0) t[15]=fmaxf(fmaxf(sm[0],sm[1]),fmaxf(sm[2],sm[3]));
}

// ---------------------------------------------------------------- scan (1M = 1024 blocks x 1024)
__global__ __launch_bounds__(256) void k_scan1(const int* cnt, int* off, int* bsum){
  __shared__ int sm[256];
  int base = blockIdx.x*1024;
  int tid = threadIdx.x;
  int4 c = *(const int4*)(cnt + base + tid*4);
  int s = c.x+c.y+c.z+c.w;
  sm[tid]=s; __syncthreads();
  int v=s;
  for(int o=1;o<256;o<<=1){
    int u = (tid>=o)? sm[tid-o]:0;
    __syncthreads();
    v += u; sm[tid]=v;
    __syncthreads();
  }
  int excl = v - s;
  int4 o4;
  o4.x=excl; o4.y=excl+c.x; o4.z=excl+c.x+c.y; o4.w=excl+c.x+c.y+c.z;
  *(int4*)(off+base+tid*4)=o4;
  if (tid==255) bsum[blockIdx.x]=v;
}

__global__ __launch_bounds__(256) void k_scan2(int* bsum){
  __shared__ int sm[256];
  int tid=threadIdx.x;
  int4 c = *(const int4*)(bsum + tid*4);
  int s = c.x+c.y+c.z+c.w;
  sm[tid]=s; __syncthreads();
  int v=s;
  for(int o=1;o<256;o<<=1){
    int u = (tid>=o)? sm[tid-o]:0;
    __syncthreads();
    v += u; sm[tid]=v;
    __syncthreads();
  }
  int excl=v-s;
  int4 o4;
  o4.x=excl; o4.y=excl+c.x; o4.z=excl+c.x+c.y; o4.w=excl+c.x+c.y+c.z;
  *(int4*)(bsum+tid*4)=o4;
}

__global__ __launch_bounds__(256) void k_scan3(int* off, const int* bbase){
  int gid = blockIdx.x*256+threadIdx.x;
  int b = bbase[gid>>8];
  int4 v = *(int4*)(off + gid*4);
  v.x+=b; v.y+=b; v.z+=b; v.w+=b;
  *(int4*)(off + gid*4)=v;
}

// ---------------------------------------------------------------- reorder (2-pass: cut scattered-write line amplification)
// pass 1: scatter only the 4B source index
__global__ __launch_bounds__(256) void k_reorder1(const float* kt, int* off, int* srcIdx){
  int m = blockIdx.x*256+threadIdx.x;
  float kx=kt[2*m], ky=kt[2*m+1];
  int ix=((int)floorf(kx*1024.f))&1023;
  int iy=((int)floorf(ky*1024.f))&1023;
  int pos = atomicAdd(&off[(ix<<10)|iy],1);
  srcIdx[pos]=m;
}

// pass 2: gather by inverse permutation; all payload writes coalesced
__global__ __launch_bounds__(256) void k_reorder2(const int* srcIdx, const float* kt,
                                                  const float* kre, const float* kim,
                                                  float2* stat, int* cellArr,
                                                  float2* ysub, float2* kdat, const float* t){
  int p = blockIdx.x*256+threadIdx.x;
  int m = srcIdx[p];
  float kx=kt[2*m], ky=kt[2*m+1];
  float gx=kx*1024.f, gy=ky*1024.f;
  float fx=floorf(gx), fy=floorf(gy);
  float tx=gx-fx, ty=gy-fy;
  int ix=((int)fx)&1023, iy=((int)fy)&1023;
  stat[p]=make_float2(tx,ty);
  cellArr[p]=(ix<<10)|iy;
  float dx=kx-0.5f, dy=ky-0.5f;
  float r=sqrtf(dx*dx+dy*dy);
  float dcf=sqrtf(r/(t[15]+1e-8f));
  ysub[p]=make_float2(kre[m]*dcf, kim[m]*dcf);
  int idx[4]; float w[4];
  corners(kx,ky,idx,w);
  float s=0.f;
#pragma unroll
  for(int q=0;q<4;q++) if (idx[q]==0) s+=w[q];
  kdat[p]=make_float2(1024.f*s,0.f);
}

// ---------------------------------------------------------------- adjoint: grid-side gather (atomic-free)
__global__ __launch_bounds__(256) void k_adj(const float2* __restrict__ stat,
                                             const float2* __restrict__ kdat,
                                             const int* __restrict__ off,
                                             float2* __restrict__ G,
                                             const float* __restrict__ t, int chain_n){
  int gid = blockIdx.x*256+threadIdx.x;
  int r = gid>>10, c = gid&1023;
  float sc = (chain_n>0)? t[20+chain_n] : 1.f;   // precomputed by reduce kernel
  float sx=0.f, sy=0.f;
#pragma unroll
  for(int dr=0;dr<2;dr++){
    int br=(r-dr)&1023;
    int rowbase = br<<10;
    if (c>0){
      int bL = rowbase|(c-1);
      int s0 = (bL==0)?0:off[bL-1];
      int mid = off[bL];
      int s1 = off[bL+1];
      for(int j=s0;j<s1;j++){
        float2 st=stat[j]; float2 v=kdat[j];
        float wxx = dr? st.x : 1.f-st.x;
        float wyy = (j<mid)? st.y : 1.f-st.y;
        float wt = wxx*wyy;
        sx=fmaf(wt,v.x,sx); sy=fmaf(wt,v.y,sy);
      }
    } else {
      int bA = rowbase|1023;
      int a0 = off[bA-1], a1 = off[bA];
      for(int j=a0;j<a1;j++){
        float2 st=stat[j]; float2 v=kdat[j];
        float wt = (dr? st.x : 1.f-st.x) * st.y;
        sx=fmaf(wt,v.x,sx); sy=fmaf(wt,v.y,sy);
      }
      int bB = rowbase;
      int b0 = (bB==0)?0:off[bB-1], b1 = off[bB];
      for(int j=b0;j<b1;j++){
        float2 st=stat[j]; float2 v=kdat[j];
        float wt = (dr? st.x : 1.f-st.x) * (1.f-st.y);
        sx=fmaf(wt,v.x,sx); sy=fmaf(wt,v.y,sy);
      }
    }
  }
  G[gid]=make_float2(sx*sc, sy*sc);
}

// ---------------------------------------------------------------- forward gather (sorted order)
__device__ __forceinline__ void fwd_point(const float2* __restrict__ G, int cellv, float2 st,
                                          float& sx, float& sy){
  int ix=cellv>>10, iy=cellv&1023;
  int ix1=(ix+1)&1023, iy1=(iy+1)&1023;
  float tx=st.x, ty=st.y, ux=1.f-tx, uy=1.f-ty;
  float2 g00=G[(ix<<10)|iy], g10=G[(ix1<<10)|iy], g01=G[(ix<<10)|iy1], g11=G[(ix1<<10)|iy1];
  float w0=ux*uy, w1=tx*uy, w2=ux*ty, w3=tx*ty;
  sx = fmaf(w0,g00.x,fmaf(w1,g10.x,fmaf(w2,g01.x,w3*g11.x)));
  sy = fmaf(w0,g00.y,fmaf(w1,g10.y,fmaf(w2,g01.y,w3*g11.y)));
}

// power-iteration gather: per-block partial dot (and ssq at last) via plain stores
__global__ __launch_bounds__(256) void k_fwd_pow(const float2* __restrict__ G,
                                                 const int* __restrict__ cellArr,
                                                 const float2* __restrict__ stat,
                                                 float2* kdat, float* part, float* part2, int last){
  int j = blockIdx.x*256+threadIdx.x;
  float dot, ssq;
  {
    float sx,sy;
    fwd_point(G,cellArr[j],stat[j],sx,sy);
    float2 old = kdat[j];
    dot = sx*old.x + sy*old.y;
    ssq = sx*sx + sy*sy;
    kdat[j]=make_float2(sx,sy);
  }
  __shared__ float sm[4];
  for(int o=32;o>0;o>>=1) dot += __shfl_down(dot,o,64);
  if((threadIdx.x&63)==0) sm[threadIdx.x>>6]=dot;
  __syncthreads();
  if(threadIdx.x==0) part[blockIdx.x]=sm[0]+sm[1]+sm[2]+sm[3];
  if (last){
    __syncthreads();
    for(int o=32;o>0;o>>=1) ssq += __shfl_down(ssq,o,64);
    if((threadIdx.x&63)==0) sm[threadIdx.x>>6]=ssq;
    __syncthreads();
    if(threadIdx.x==0) part2[blockIdx.x]=sm[0]+sm[1]+sm[2]+sm[3];
  }
}

// reduce partial dots -> t[n]; precompute next adjoint scale t[21+n]
__global__ __launch_bounds__(256) void k_reduce_chain(const float* part, float* t, int n){
  int tid=threadIdx.x;
  float s=0.f;
  for(int k=tid;k<2048;k+=256) s+=part[k];
  __shared__ float sm[4];
  for(int o=32;o>0;o>>=1) s+=__shfl_down(s,o,64);
  if((tid&63)==0) sm[tid>>6]=s;
  __syncthreads();
  if(tid==0){
    float sum=sm[0]+sm[1]+sm[2]+sm[3];
    t[n]=sum;
    float tv = (n==0)? sum : t[0];
    for(int k=1;k<=n;k++){ float val=(k==n)? sum : t[k]; tv = val/(sqrtf(tv)+1e-12f); }
    t[21+n] = 1.f/(sqrtf(tv)+1e-12f);
  }
}

// final reduce: t[8], t[10]=ssq, then w_reg -> t[19]
__global__ __launch_bounds__(256) void k_reduce_last(const float* part, const float* part2,
                                                     const float* wraw, float* t){
  int tid=threadIdx.x;
  float s1=0.f, s2=0.f;
  for(int k=tid;k<2048;k+=256){ s1+=part[k]; s2+=part2[k]; }
  __shared__ float sm[8];
  for(int o=32;o>0;o>>=1){ s1+=__shfl_down(s1,o,64); s2+=__shfl_down(s2,o,64); }
  if((tid&63)==0){ sm[tid>>6]=s1; sm[4+(tid>>6)]=s2; }
  __syncthreads();
  if(tid==0){
    float sum=sm[0]+sm[1]+sm[2]+sm[3];
    float ssq=sm[4]+sm[5]+sm[6]+sm[7];
    t[8]=sum; t[10]=ssq;
    float tv=t[0];
    for(int k=1;k<=8;k++){ float val=(k==8)? sum : t[k]; tv = val/(sqrtf(tv)+1e-12f); }
    float c9=1.f/(sqrtf(tv)+1e-12f);
    float avn=c9*sqrtf(ssq);
    float vn=sqrtf(tv)*c9;
    float opn=avn/(vn+1e-12f);
    float sig=1.f/(1.f+__expf(-wraw[0]));
    t[19]=2.f*sig/(opn*opn);
  }
}

__global__ __launch_bounds__(256) void k_fwd_sub(const float2* __restrict__ G,
                                                 const int* __restrict__ cellArr,
                                                 const float2* __restrict__ stat,
                                                 const float2* __restrict__ ysub,
                                                 float2* kdat){
  int j = blockIdx.x*256+threadIdx.x;
  float sx,sy;
  fwd_point(G,cellArr[j],stat[j],sx,sy);
  float2 yv = ysub[j];
  kdat[j]=make_float2(sx-yv.x, sy-yv.y);
}

// ---------------------------------------------------------------- composed-conv tables
// ec layout (floats): [0..99] E[oc*50+ic*25+dy*5+dx]; [100..101] C0;
// [102..119] Bb[oc*9+u]; [120..443] Btab[oc*162+u*18+ic*9+v]; [444..445] b2
__global__ __launch_bounds__(256) void k_mkE(const float* w1, const float* b1,
                                             const float* w2, const float* b2, float* ec){
  __shared__ float sw1[576], sw2[576], sb1[32], sB[324];
  int tid=threadIdx.x;
  for(int p=tid;p<576;p+=256){ sw1[p]=w1[p]; sw2[p]=w2[p]; }
  if(tid<32) sb1[tid]=b1[tid];
  __syncthreads();
  for(int e=tid;e<324;e+=256){
    int oc=e/162, r=e-oc*162, u=r/18, r2=r-u*18, ic=r2/9, v=r2-ic*9;
    float s=0.f;
    for(int cm=0;cm<32;cm++) s=fmaf(sw2[oc*288+cm*9+u], sw1[cm*18+ic*9+v], s);
    sB[e]=s; ec[120+e]=s;
  }
  if(tid<18){
    int oc=tid/9, u=tid-oc*9;
    float s=0.f;
    for(int cm=0;cm<32;cm++) s=fmaf(sw2[oc*288+cm*9+u], sb1[cm], s);
    ec[102+tid]=s;
  }
  if(tid<2){
    float s=b2[tid];
    for(int u=0;u<9;u++){
      float bb=0.f;
      for(int cm=0;cm<32;cm++) bb=fmaf(sw2[tid*288+cm*9+u], sb1[cm], bb);
      s+=bb;
    }
    ec[100+tid]=s;
    ec[444+tid]=b2[tid];
  }
  __syncthreads();
  if(tid<100){
    int oc=tid/50, r=tid-oc*50, ic=r/25, r2=r-ic*25, dy=r2/5, dx=r2-dy*5;
    float s=0.f;
    for(int uy=0;uy<3;uy++){ int vy=dy-uy; if(vy<0||vy>2) continue;
      for(int ux=0;ux<3;ux++){ int vx=dx-ux; if(vx<0||vx>2) continue;
        s+=sB[oc*162+(uy*3+ux)*18+ic*9+vy*3+vx];
      }
    }
    ec[tid]=s;
  }
}

// ---------------------------------------------------------------- fused 5x5 composed CNN + update
#define CT_S 40
__global__ __launch_bounds__(256) void k_cnn5(const float2* __restrict__ x, const float2* __restrict__ res,
    const float* __restrict__ ec, const float* __restrict__ t,
    float2* __restrict__ xout, float* __restrict__ outPlanar){
  __shared__ __align__(16) float xt0[36*CT_S];
  __shared__ __align__(16) float xt1[36*CT_S];
  __shared__ float sE[446];
  int tid=threadIdx.x;
  int by=blockIdx.x>>5, bx=blockIdx.x&31;
  int ty0=by<<5, tx0=bx<<5;
  for(int p=tid;p<446;p+=256) sE[p]=ec[p];
  for(int p=tid;p<1296;p+=256){
    int r=p/36, c=p-r*36;
    int gy=ty0-2+r, gx=tx0-2+c;
    float vx=0.f, vy=0.f;
    if((unsigned)gy<1024u && (unsigned)gx<1024u){ float2 v=x[(size_t)gy*W_+gx]; vx=v.x; vy=v.y; }
    xt0[r*CT_S+c]=vx; xt1[r*CT_S+c]=vy;
  }
  __syncthreads();
  int row=tid>>3, c4=(tid&7)<<2;
  float a0[4], a1[4];
  float C00=sE[100], C01=sE[101];
#pragma unroll
  for(int jj=0;jj<4;jj++){ a0[jj]=C00; a1[jj]=C01; }
#pragma unroll
  for(int dy=0;dy<5;dy++){
    const float* r0=&xt0[(row+dy)*CT_S+c4];
    const float* r1=&xt1[(row+dy)*CT_S+c4];
    float f0[9], f1[9];
#pragma unroll
    for(int q=0;q<9;q++){ f0[q]=r0[q]; f1[q]=r1[q]; }
#pragma unroll
    for(int dx=0;dx<5;dx++){
      float e00=sE[dy*5+dx], e01=sE[25+dy*5+dx];
      float e10=sE[50+dy*5+dx], e11=sE[75+dy*5+dx];
#pragma unroll
      for(int jj=0;jj<4;jj++){
        a0[jj]=fmaf(e00,f0[jj+dx],fmaf(e01,f1[jj+dx],a0[jj]));
        a1[jj]=fmaf(e10,f0[jj+dx],fmaf(e11,f1[jj+dx],a1[jj]));
      }
    }
  }
  int py=ty0+row;
  // exact border ring: conv2 sees h=0 outside image, not the composed extension
  bool rowEdge = (py==0)||(py==1023);
  if (rowEdge || (tx0+c4)==0 || (tx0+c4+3)==1023){
    for(int jj=0;jj<4;jj++){
      int px=tx0+c4+jj;
      if(!(rowEdge || px==0 || px==1023)) continue;
      float s0=sE[444], s1=sE[445];
      for(int uy=0;uy<3;uy++){
        int qy=py+uy-1; if((unsigned)qy>=1024u) continue;
        for(int ux=0;ux<3;ux++){
          int qx=px+ux-1; if((unsigned)qx>=1024u) continue;
          int u=uy*3+ux;
          s0+=sE[102+u]; s1+=sE[111+u];
          const float* B0=&sE[120+u*18];
          const float* B1=&sE[282+u*18];
          for(int vy=0;vy<3;vy++){
            for(int vx=0;vx<3;vx++){
              int v=vy*3+vx;
              float xv0=xt0[(row+uy+vy)*CT_S + c4+jj+ux+vx];
              float xv1=xt1[(row+uy+vy)*CT_S + c4+jj+ux+vx];
              s0 = fmaf(B0[v],xv0,fmaf(B0[9+v],xv1,s0));
              s1 = fmaf(B1[v],xv0,fmaf(B1[9+v],xv1,s1));
            }
          }
        }
      }
      a0[jj]=s0; a1[jj]=s1;
    }
  }
  float wreg = t[19];
  size_t base=(size_t)py*W_ + tx0 + c4;
  if (outPlanar){
#pragma unroll
    for(int jj=0;jj<4;jj++){
      float2 rv=res[base+jj];
      float xr_=xt0[(row+2)*CT_S+c4+jj+2];
      float xi_=xt1[(row+2)*CT_S+c4+jj+2];
      outPlanar[base+jj]      = xr_ - wreg*rv.x - a0[jj];
      outPlanar[HW_+base+jj]  = xi_ - wreg*rv.y - a1[jj];
    }
  } else {
#pragma unroll
    for(int jj=0;jj<4;jj++){
      float2 rv=res[base+jj];
      float xr_=xt0[(row+2)*CT_S+c4+jj+2];
      float xi_=xt1[(row+2)*CT_S+c4+jj+2];
      xout[base+jj]=make_float2(xr_ - wreg*rv.x - a0[jj],
                                xi_ - wreg*rv.y - a1[jj]);
    }
  }
}

// ================================================================ launch
extern "C" void kernel_launch(void* const* d_in, const int* in_sizes, int n_in,
                              void* d_out, int out_size, void* d_ws, size_t ws_size,
                              hipStream_t stream){
  (void)in_sizes; (void)n_in; (void)out_size; (void)ws_size;
  const float* xr  =(const float*)d_in[0];
  const float* xi  =(const float*)d_in[1];
  const float* kre =(const float*)d_in[2];
  const float* kim =(const float*)d_in[3];
  const float* kt  =(const float*)d_in[4];
  const float* wraw=(const float*)d_in[5];
  const float* w1  =(const float*)d_in[6];
  const float* b1  =(const float*)d_in[7];
  const float* w2  =(const float*)d_in[8];
  const float* b2  =(const float*)d_in[9];
  float* out = (float*)d_out;

  char* ws=(char*)d_ws;
  float2* Wx0 =(float2*)(ws);                      // 8MB
  float2* Wx1 =(float2*)(ws + ((size_t) 8<<20));   // 8MB
  int*   counts=(int*)   (ws + ((size_t) 8<<20));  // 4MB alias of Wx1 (setup only)
  int*   srcIdx=(int*)   (ws + ((size_t)12<<20));  // 2MB alias of Wx1 tail (setup only)
  float2* WF  =(float2*)(ws + ((size_t)16<<20));   // 8MB
  float2* kdat=(float2*)(ws + ((size_t)24<<20));   // 4MB
  float2* stat=(float2*)(ws + ((size_t)28<<20));   // 4MB
  float2* ysub=(float2*)(ws + ((size_t)32<<20));   // 4MB
  int*  cellA =(int*)   (ws + ((size_t)36<<20));   // 2MB
  int*  off   =(int*)   (ws + ((size_t)38<<20));   // 4MB
  int*  bsum  =(int*)   (ws + ((size_t)42<<20));   // 4KB
  float* t    =(float*) (ws + ((size_t)42<<20) + 8192);
  float* ec   =(float*) (ws + ((size_t)42<<20) + 16384);
  float* part =(float*) (ws + ((size_t)42<<20) + 32768);
  float* part2=(float*) (ws + ((size_t)42<<20) + 40960);
  float* pmax =(float*) (ws + ((size_t)42<<20) + 49152);
  const float SC = 0.03125f;   // 1/32 per 1-D ortho pass

  // ---- setup
  k_pack<<<HW_/256,256,0,stream>>>(xr,xi,Wx0,t);
  k_mkE<<<1,256,0,stream>>>(w1,b1,w2,b2,ec);
  hipMemsetAsync(counts,0,(size_t)HW_*sizeof(int),stream);
  k_hist<<<M_/256,256,0,stream>>>(kt,counts,pmax);
  k_reduce_max<<<1,256,0,stream>>>(pmax,t);
  k_scan1<<<1024,256,0,stream>>>(counts,off,bsum);
  k_scan2<<<1,256,0,stream>>>(bsum);
  k_scan3<<<1024,256,0,stream>>>(off,bsum);
  k_reorder1<<<M_/256,256,0,stream>>>(kt,off,srcIdx);
  k_reorder2<<<M_/256,256,0,stream>>>(srcIdx,kt,kre,kim,stat,cellA,ysub,kdat,t);

  // ---- power iteration, fully in k-space (fft2/ifft2 cancel; Parseval for norms)
  for (int n=0;n<9;n++){
    k_adj<<<HW_/256,256,0,stream>>>(stat,kdat,off,WF,t,n);
    k_fwd_pow<<<M_/256,256,0,stream>>>(WF,cellA,stat,kdat,part,part2,(n==8)?1:0);
    if (n<8) k_reduce_chain<<<1,256,0,stream>>>(part,t,n);
    else     k_reduce_last <<<1,256,0,stream>>>(part,part2,wraw,t);
  }

  // ---- npcg = 4 PGD iterations
  for (int it=0; it<4; it++){
    float2* xin  = (it&1)? Wx1 : Wx0;
    float2* xout = (it&1)? Wx0 : Wx1;
    k_fft_rows<-1><<<H_,256,0,stream>>>(xin,WF,SC);
    k_fft_cols<-1><<<W_/4,256,0,stream>>>(WF,SC);
    k_fwd_sub<<<M_/256,256,0,stream>>>(WF,cellA,stat,ysub,kdat);
    k_adj<<<HW_/256,256,0,stream>>>(stat,kdat,off,WF,t,-1);
    k_fft_rows<1><<<H_,256,0,stream>>>(WF,WF,SC);
    k_fft_cols<1><<<W_/4,256,0,stream>>>(WF,SC);
    k_cnn5<<<1024,256,0,stream>>>(xin,WF,ec,t,xout,(it==3)? out : (float*)nullptr);
  }
}

// Round 5
// 768.024 us; speedup vs baseline: 5.1252x; 1.0981x over previous
//
#include <hip/hip_runtime.h>

#define H_  1024
#define W_  1024
#define HW_ (H_*W_)
#define M_  524288

#define SWZ(a) ((a) + ((a)>>4))

// ---------------------------------------------------------------- complex mul
__device__ __forceinline__ float2 cmulf(float2 a, float2 b){
  return make_float2(fmaf(a.x,b.x,-(a.y*b.y)), fmaf(a.x,b.y,a.y*b.x));
}

// ---------------------------------------------------------------- radix-4 bfly
template<int DIR>
__device__ __forceinline__ void bfly4(float2 v[4], int j, int Ns){
  if (Ns>1){
    float ang = ((DIR>0)?6.28318530717958647692f:-6.28318530717958647692f)
                * (float)(j&(Ns-1)) / (float)(4*Ns);
    float s,c; __sincosf(ang,&s,&c);
    float2 w1=make_float2(c,s);
    float2 w2=cmulf(w1,w1);
    float2 w3=cmulf(w2,w1);
    v[1]=cmulf(v[1],w1); v[2]=cmulf(v[2],w2); v[3]=cmulf(v[3],w3);
  }
  float2 t0=make_float2(v[0].x+v[2].x, v[0].y+v[2].y);
  float2 t2=make_float2(v[0].x-v[2].x, v[0].y-v[2].y);
  float2 t1=make_float2(v[1].x+v[3].x, v[1].y+v[3].y);
  float2 t3=make_float2(v[1].x-v[3].x, v[1].y-v[3].y);
  float2 t3r=(DIR<0)?make_float2(t3.y,-t3.x):make_float2(-t3.y,t3.x);
  v[0]=make_float2(t0.x+t1.x,  t0.y+t1.y);
  v[1]=make_float2(t2.x+t3r.x, t2.y+t3r.y);
  v[2]=make_float2(t0.x-t1.x,  t0.y-t1.y);
  v[3]=make_float2(t2.x-t3r.x, t2.y-t3r.y);
}

template<int DIR, int NS>
__device__ __forceinline__ void fft_stage(int j, const float2* src, float2* dst){
  float2 v[4];
#pragma unroll
  for(int r=0;r<4;r++) v[r]=src[SWZ(j+256*r)];
  bfly4<DIR>(v,j,NS);
  int base = ((j & ~(NS-1))<<2) | (j&(NS-1));
#pragma unroll
  for(int r=0;r<4;r++) dst[SWZ(base+NS*r)]=v[r];
}

template<int DIR>
__device__ __forceinline__ void fft1024_core(float2 v[4], int j, float2* A, float2* B, float scale){
  bfly4<DIR>(v,j,1);
#pragma unroll
  for(int r=0;r<4;r++) A[SWZ(4*j+r)]=v[r];
  __syncthreads();
  fft_stage<DIR,4 >(j,A,B); __syncthreads();
  fft_stage<DIR,16>(j,B,A); __syncthreads();
  fft_stage<DIR,64>(j,A,B); __syncthreads();
#pragma unroll
  for(int r=0;r<4;r++) v[r]=B[SWZ(j+256*r)];
  bfly4<DIR>(v,j,256);
#pragma unroll
  for(int r=0;r<4;r++){ v[r].x*=scale; v[r].y*=scale; }
}

template<int DIR>
__global__ __launch_bounds__(256) void k_fft_rows(const float2* src, float2* dst, float scale){
  __shared__ float2 A[1088], B[1088];
  int j = threadIdx.x;
  const float2* s = src + (size_t)blockIdx.x*W_;
  float2 v[4];
#pragma unroll
  for(int r=0;r<4;r++) v[r]=s[j+256*r];
  fft1024_core<DIR>(v,j,A,B,scale);
  float2* d = dst + (size_t)blockIdx.x*W_;
#pragma unroll
  for(int r=0;r<4;r++) d[j+256*r]=v[r];
}

template<int DIR>
__global__ __launch_bounds__(256) void k_fft_cols(float2* data, float scale){
  __shared__ float2 T[4*1025];
  __shared__ float2 A[1088], B[1088];
  int tid=threadIdx.x, c0=blockIdx.x*4;
#pragma unroll
  for(int k=0;k<16;k++){
    int idx=tid+256*k; int c=idx&3, r=idx>>2;
    T[c*1025+r]=data[(size_t)r*W_ + c0 + c];
  }
  __syncthreads();
  for(int c=0;c<4;c++){
    float2* col = T + c*1025;
    float2 v[4];
#pragma unroll
    for(int r=0;r<4;r++) v[r]=col[tid+256*r];
    fft1024_core<DIR>(v,tid,A,B,scale);
#pragma unroll
    for(int r=0;r<4;r++) col[tid+256*r]=v[r];
  }
  __syncthreads();
#pragma unroll
  for(int k=0;k<16;k++){
    int idx=tid+256*k; int c=idx&3, r=idx>>2;
    data[(size_t)r*W_ + c0 + c]=T[c*1025+r];
  }
}

// ---------------------------------------------------------------- interp helpers
__device__ __forceinline__ void corners(float kx, float ky, int idx[4], float w[4]){
  float gx = kx*1024.f, gy = ky*1024.f;
  float fx = floorf(gx), fy = floorf(gy);
  float tx = gx-fx, ty = gy-fy;
  int ix = ((int)fx)&1023, iy = ((int)fy)&1023;
  int ix1=(ix+1)&1023, iy1=(iy+1)&1023;
  idx[0]=(ix<<10)|iy;  idx[1]=(ix1<<10)|iy;
  idx[2]=(ix<<10)|iy1; idx[3]=(ix1<<10)|iy1;
  float ux=1.f-tx, uy=1.f-ty;
  w[0]=ux*uy; w[1]=tx*uy; w[2]=ux*ty; w[3]=tx*ty;
}

// ---------------------------------------------------------------- init
__global__ __launch_bounds__(256) void k_pack(const float* xr, const float* xi, float2* X, float* t){
  int i = blockIdx.x*256+threadIdx.x;
  if (i<HW_) X[i]=make_float2(xr[i],xi[i]);
  if (blockIdx.x==0 && threadIdx.x<32) t[threadIdx.x]=0.f;
}

// histogram by base cell + per-block max radius
__global__ __launch_bounds__(256) void k_hist(const float* kt, int* counts, float* pmax){
  int m = blockIdx.x*256+threadIdx.x;
  float r = 0.f;
  {
    float kx=kt[2*m], ky=kt[2*m+1];
    float dx=kx-0.5f, dy=ky-0.5f;
    r = sqrtf(dx*dx+dy*dy);
    int ix = ((int)floorf(kx*1024.f))&1023;
    int iy = ((int)floorf(ky*1024.f))&1023;
    atomicAdd(&counts[(ix<<10)|iy],1);
  }
  for(int o=32;o>0;o>>=1) r = fmaxf(r, __shfl_down(r,o,64));
  __shared__ float sm[4];
  if((threadIdx.x&63)==0) sm[threadIdx.x>>6]=r;
  __syncthreads();
  if(threadIdx.x==0)
    pmax[blockIdx.x] = fmaxf(fmaxf(sm[0],sm[1]),fmaxf(sm[2],sm[3]));
}

__global__ __launch_bounds__(256) void k_reduce_max(const float* pmax, float* t){
  int tid=threadIdx.x;
  float s=-1e30f;
  for(int k=tid;k<2048;k+=256) s=fmaxf(s,pmax[k]);
  __shared__ float sm[4];
  for(int o=32;o>0;o>>=1) s=fmaxf(s,__shfl_down(s,o,64));
  if((tid&63)==0) sm[tid>>6]=s;
  __syncthreads();
  if(tid==0) t[15]=fmaxf(fmaxf(sm[0],sm[1]),fmaxf(sm[2],sm[3]));
}

// ---------------------------------------------------------------- scan (1M = 1024 blocks x 1024)
__global__ __launch_bounds__(256) void k_scan1(const int* cnt, int* off, int* bsum){
  __shared__ int sm[256];
  int base = blockIdx.x*1024;
  int tid = threadIdx.x;
  int4 c = *(const int4*)(cnt + base + tid*4);
  int s = c.x+c.y+c.z+c.w;
  sm[tid]=s; __syncthreads();
  int v=s;
  for(int o=1;o<256;o<<=1){
    int u = (tid>=o)? sm[tid-o]:0;
    __syncthreads();
    v += u; sm[tid]=v;
    __syncthreads();
  }
  int excl = v - s;
  int4 o4;
  o4.x=excl; o4.y=excl+c.x; o4.z=excl+c.x+c.y; o4.w=excl+c.x+c.y+c.z;
  *(int4*)(off+base+tid*4)=o4;
  if (tid==255) bsum[blockIdx.x]=v;
}

__global__ __launch_bounds__(256) void k_scan2(int* bsum){
  __shared__ int sm[256];
  int tid=threadIdx.x;
  int4 c = *(const int4*)(bsum + tid*4);
  int s = c.x+c.y+c.z+c.w;
  sm[tid]=s; __syncthreads();
  int v=s;
  for(int o=1;o<256;o<<=1){
    int u = (tid>=o)? sm[tid-o]:0;
    __syncthreads();
    v += u; sm[tid]=v;
    __syncthreads();
  }
  int excl=v-s;
  int4 o4;
  o4.x=excl; o4.y=excl+c.x; o4.z=excl+c.x+c.y; o4.w=excl+c.x+c.y+c.z;
  *(int4*)(bsum+tid*4)=o4;
}

__global__ __launch_bounds__(256) void k_scan3(int* off, const int* bbase){
  int gid = blockIdx.x*256+threadIdx.x;
  int b = bbase[gid>>8];
  int4 v = *(int4*)(off + gid*4);
  v.x+=b; v.y+=b; v.z+=b; v.w+=b;
  *(int4*)(off + gid*4)=v;
}

// ---------------------------------------------------------------- reorder (2-pass)
__global__ __launch_bounds__(256) void k_reorder1(const float* kt, int* off, int* srcIdx){
  int m = blockIdx.x*256+threadIdx.x;
  float kx=kt[2*m], ky=kt[2*m+1];
  int ix=((int)floorf(kx*1024.f))&1023;
  int iy=((int)floorf(ky*1024.f))&1023;
  int pos = atomicAdd(&off[(ix<<10)|iy],1);
  srcIdx[pos]=m;
}

__global__ __launch_bounds__(256) void k_reorder2(const int* srcIdx, const float* kt,
                                                  const float* kre, const float* kim,
                                                  float2* stat, int* cellArr,
                                                  float2* ysub, float2* kdat, const float* t){
  int p = blockIdx.x*256+threadIdx.x;
  int m = srcIdx[p];
  float kx=kt[2*m], ky=kt[2*m+1];
  float gx=kx*1024.f, gy=ky*1024.f;
  float fx=floorf(gx), fy=floorf(gy);
  float tx=gx-fx, ty=gy-fy;
  int ix=((int)fx)&1023, iy=((int)fy)&1023;
  stat[p]=make_float2(tx,ty);
  cellArr[p]=(ix<<10)|iy;
  float dx=kx-0.5f, dy=ky-0.5f;
  float r=sqrtf(dx*dx+dy*dy);
  float dcf=sqrtf(r/(t[15]+1e-8f));
  ysub[p]=make_float2(kre[m]*dcf, kim[m]*dcf);
  int idx[4]; float w[4];
  corners(kx,ky,idx,w);
  float s=0.f;
#pragma unroll
  for(int q=0;q<4;q++) if (idx[q]==0) s+=w[q];
  kdat[p]=make_float2(1024.f*s,0.f);
}

// ---------------------------------------------------------------- adjoint: 4 cells/thread, contiguous CSR range
__global__ __launch_bounds__(256) void k_adj(const float2* __restrict__ stat,
                                             const float2* __restrict__ kdat,
                                             const int* __restrict__ off,
                                             float2* __restrict__ G,
                                             const float* __restrict__ t, int chain_n){
  int gid = blockIdx.x*256+threadIdx.x;       // 262144 threads, 4 cells each
  int r  = gid>>8;
  int c0 = (gid&255)<<2;
  float sc = (chain_n>0)? t[20+chain_n] : 1.f;
  float axr[4]={0.f,0.f,0.f,0.f}, ayr[4]={0.f,0.f,0.f,0.f};
#pragma unroll
  for(int dr=0;dr<2;dr++){
    int br=(r-dr)&1023;
    int rowbase=br<<10;
    if (c0>0){
      // bins c0-1 .. c0+3 contiguous; O[i]..O[i+1] = bin (c0-1+i)
      int O[6];
#pragma unroll
      for(int q=0;q<6;q++) O[q]=off[rowbase+c0-2+q];
#pragma unroll
      for(int i=0;i<5;i++){
        for(int j=O[i]; j<O[i+1]; j++){
          float2 st=stat[j]; float2 v=kdat[j];
          float wx = dr ? st.x : 1.f-st.x;
          float w0 = wx*(1.f-st.y), w1 = wx*st.y;
          if (i>=1){ axr[i-1]=fmaf(w0,v.x,axr[i-1]); ayr[i-1]=fmaf(w0,v.y,ayr[i-1]); }
          if (i<=3){ axr[i]  =fmaf(w1,v.x,axr[i]);   ayr[i]  =fmaf(w1,v.y,ayr[i]); }
        }
      }
    } else {
      // wrap: bin col 1023 contributes ty-side to col 0
      int bw = rowbase+1023;
      int sw = off[bw-1], ew=off[bw];
      for(int j=sw;j<ew;j++){
        float2 st=stat[j]; float2 v=kdat[j];
        float wx = dr ? st.x : 1.f-st.x;
        float w1 = wx*st.y;
        axr[0]=fmaf(w1,v.x,axr[0]); ayr[0]=fmaf(w1,v.y,ayr[0]);
      }
      int O[5];
      O[0] = (rowbase==0)? 0 : off[rowbase-1];
#pragma unroll
      for(int q=1;q<5;q++) O[q]=off[rowbase+q-1];
#pragma unroll
      for(int i=0;i<4;i++){
        for(int j=O[i]; j<O[i+1]; j++){
          float2 st=stat[j]; float2 v=kdat[j];
          float wx = dr ? st.x : 1.f-st.x;
          float w0 = wx*(1.f-st.y), w1 = wx*st.y;
          axr[i]=fmaf(w0,v.x,axr[i]); ayr[i]=fmaf(w0,v.y,ayr[i]);
          if (i<=2){ axr[i+1]=fmaf(w1,v.x,axr[i+1]); ayr[i+1]=fmaf(w1,v.y,ayr[i+1]); }
        }
      }
    }
  }
  size_t base=((size_t)r<<10)+c0;
#pragma unroll
  for(int q=0;q<4;q++) G[base+q]=make_float2(axr[q]*sc, ayr[q]*sc);
}

// ---------------------------------------------------------------- forward gather (sorted order)
__device__ __forceinline__ void fwd_point(const float2* __restrict__ G, int cellv, float2 st,
                                          float& sx, float& sy){
  int ix=cellv>>10, iy=cellv&1023;
  int ix1=(ix+1)&1023, iy1=(iy+1)&1023;
  float tx=st.x, ty=st.y, ux=1.f-tx, uy=1.f-ty;
  float2 g00=G[(ix<<10)|iy], g10=G[(ix1<<10)|iy], g01=G[(ix<<10)|iy1], g11=G[(ix1<<10)|iy1];
  float w0=ux*uy, w1=tx*uy, w2=ux*ty, w3=tx*ty;
  sx = fmaf(w0,g00.x,fmaf(w1,g10.x,fmaf(w2,g01.x,w3*g11.x)));
  sy = fmaf(w0,g00.y,fmaf(w1,g10.y,fmaf(w2,g01.y,w3*g11.y)));
}

__global__ __launch_bounds__(256) void k_fwd_pow(const float2* __restrict__ G,
                                                 const int* __restrict__ cellArr,
                                                 const float2* __restrict__ stat,
                                                 float2* kdat, float* part, float* part2, int last){
  int j = blockIdx.x*256+threadIdx.x;
  float dot, ssq;
  {
    float sx,sy;
    fwd_point(G,cellArr[j],stat[j],sx,sy);
    float2 old = kdat[j];
    dot = sx*old.x + sy*old.y;
    ssq = sx*sx + sy*sy;
    kdat[j]=make_float2(sx,sy);
  }
  __shared__ float sm[4];
  for(int o=32;o>0;o>>=1) dot += __shfl_down(dot,o,64);
  if((threadIdx.x&63)==0) sm[threadIdx.x>>6]=dot;
  __syncthreads();
  if(threadIdx.x==0) part[blockIdx.x]=sm[0]+sm[1]+sm[2]+sm[3];
  if (last){
    __syncthreads();
    for(int o=32;o>0;o>>=1) ssq += __shfl_down(ssq,o,64);
    if((threadIdx.x&63)==0) sm[threadIdx.x>>6]=ssq;
    __syncthreads();
    if(threadIdx.x==0) part2[blockIdx.x]=sm[0]+sm[1]+sm[2]+sm[3];
  }
}

__global__ __launch_bounds__(256) void k_reduce_chain(const float* part, float* t, int n){
  int tid=threadIdx.x;
  float s=0.f;
  for(int k=tid;k<2048;k+=256) s+=part[k];
  __shared__ float sm[4];
  for(int o=32;o>0;o>>=1) s+=__shfl_down(s,o,64);
  if((tid&63)==0) sm[tid>>6]=s;
  __syncthreads();
  if(tid==0){
    float sum=sm[0]+sm[1]+sm[2]+sm[3];
    t[n]=sum;
    float tv = (n==0)? sum : t[0];
    for(int k=1;k<=n;k++){ float val=(k==n)? sum : t[k]; tv = val/(sqrtf(tv)+1e-12f); }
    t[21+n] = 1.f/(sqrtf(tv)+1e-12f);
  }
}

__global__ __launch_bounds__(256) void k_reduce_last(const float* part, const float* part2,
                                                     const float* wraw, float* t){
  int tid=threadIdx.x;
  float s1=0.f, s2=0.f;
  for(int k=tid;k<2048;k+=256){ s1+=part[k]; s2+=part2[k]; }
  __shared__ float sm[8];
  for(int o=32;o>0;o>>=1){ s1+=__shfl_down(s1,o,64); s2+=__shfl_down(s2,o,64); }
  if((tid&63)==0){ sm[tid>>6]=s1; sm[4+(tid>>6)]=s2; }
  __syncthreads();
  if(tid==0){
    float sum=sm[0]+sm[1]+sm[2]+sm[3];
    float ssq=sm[4]+sm[5]+sm[6]+sm[7];
    t[8]=sum; t[10]=ssq;
    float tv=t[0];
    for(int k=1;k<=8;k++){ float val=(k==8)? sum : t[k]; tv = val/(sqrtf(tv)+1e-12f); }
    float c9=1.f/(sqrtf(tv)+1e-12f);
    float avn=c9*sqrtf(ssq);
    float vn=sqrtf(tv)*c9;
    float opn=avn/(vn+1e-12f);
    float sig=1.f/(1.f+__expf(-wraw[0]));
    t[19]=2.f*sig/(opn*opn);
  }
}

__global__ __launch_bounds__(256) void k_fwd_sub(const float2* __restrict__ G,
                                                 const int* __restrict__ cellArr,
                                                 const float2* __restrict__ stat,
                                                 const float2* __restrict__ ysub,
                                                 float2* kdat){
  int j = blockIdx.x*256+threadIdx.x;
  float sx,sy;
  fwd_point(G,cellArr[j],stat[j],sx,sy);
  float2 yv = ysub[j];
  kdat[j]=make_float2(sx-yv.x, sy-yv.y);
}

// ---------------------------------------------------------------- composed-conv tables
// ec layout (floats): [0..99] E[oc*50+ic*25+dy*5+dx]; [100..101] C0;
// [102..119] Bb[oc*9+u]; [120..443] Btab[oc*162+u*18+ic*9+v]; [444..445] b2
__global__ __launch_bounds__(256) void k_mkE(const float* w1, const float* b1,
                                             const float* w2, const float* b2, float* ec){
  __shared__ float sw1[576], sw2[576], sb1[32], sB[324];
  int tid=threadIdx.x;
  for(int p=tid;p<576;p+=256){ sw1[p]=w1[p]; sw2[p]=w2[p]; }
  if(tid<32) sb1[tid]=b1[tid];
  __syncthreads();
  for(int e=tid;e<324;e+=256){
    int oc=e/162, r=e-oc*162, u=r/18, r2=r-u*18, ic=r2/9, v=r2-ic*9;
    float s=0.f;
    for(int cm=0;cm<32;cm++) s=fmaf(sw2[oc*288+cm*9+u], sw1[cm*18+ic*9+v], s);
    sB[e]=s; ec[120+e]=s;
  }
  if(tid<18){
    int oc=tid/9, u=tid-oc*9;
    float s=0.f;
    for(int cm=0;cm<32;cm++) s=fmaf(sw2[oc*288+cm*9+u], sb1[cm], s);
    ec[102+tid]=s;
  }
  if(tid<2){
    float s=b2[tid];
    for(int u=0;u<9;u++){
      float bb=0.f;
      for(int cm=0;cm<32;cm++) bb=fmaf(sw2[tid*288+cm*9+u], sb1[cm], bb);
      s+=bb;
    }
    ec[100+tid]=s;
    ec[444+tid]=b2[tid];
  }
  __syncthreads();
  if(tid<100){
    int oc=tid/50, r=tid-oc*50, ic=r/25, r2=r-ic*25, dy=r2/5, dx=r2-dy*5;
    float s=0.f;
    for(int uy=0;uy<3;uy++){ int vy=dy-uy; if(vy<0||vy>2) continue;
      for(int ux=0;ux<3;ux++){ int vx=dx-ux; if(vx<0||vx>2) continue;
        s+=sB[oc*162+(uy*3+ux)*18+ic*9+vy*3+vx];
      }
    }
    ec[tid]=s;
  }
}

// ---------------------------------------------------------------- fused 5x5 composed CNN + update (interior-exact; ring fixed by k_cnnb)
#define CT_S 41
__global__ __launch_bounds__(256) void k_cnn5(const float2* __restrict__ x, const float2* __restrict__ res,
    const float* __restrict__ ec, const float* __restrict__ t,
    float2* __restrict__ xout, float* __restrict__ outPlanar){
  __shared__ float xt0[36*CT_S];
  __shared__ float xt1[36*CT_S];
  __shared__ float sE[102];
  int tid=threadIdx.x;
  int by=blockIdx.x>>5, bx=blockIdx.x&31;
  int ty0=by<<5, tx0=bx<<5;
  for(int p=tid;p<102;p+=256) sE[p]=ec[p];
  for(int p=tid;p<1296;p+=256){
    int r=p/36, c=p-r*36;
    int gy=ty0-2+r, gx=tx0-2+c;
    float vx=0.f, vy=0.f;
    if((unsigned)gy<1024u && (unsigned)gx<1024u){ float2 v=x[(size_t)gy*W_+gx]; vx=v.x; vy=v.y; }
    xt0[r*CT_S+c]=vx; xt1[r*CT_S+c]=vy;
  }
  __syncthreads();
  int row=tid>>3, c4=(tid&7)<<2;
  float a0[4], a1[4];
  float C00=sE[100], C01=sE[101];
#pragma unroll
  for(int jj=0;jj<4;jj++){ a0[jj]=C00; a1[jj]=C01; }
#pragma unroll
  for(int dy=0;dy<5;dy++){
    const float* r0=&xt0[(row+dy)*CT_S+c4];
    const float* r1=&xt1[(row+dy)*CT_S+c4];
    float f0[9], f1[9];
#pragma unroll
    for(int q=0;q<9;q++){ f0[q]=r0[q]; f1[q]=r1[q]; }
#pragma unroll
    for(int dx=0;dx<5;dx++){
      float e00=sE[dy*5+dx], e01=sE[25+dy*5+dx];
      float e10=sE[50+dy*5+dx], e11=sE[75+dy*5+dx];
#pragma unroll
      for(int jj=0;jj<4;jj++){
        a0[jj]=fmaf(e00,f0[jj+dx],fmaf(e01,f1[jj+dx],a0[jj]));
        a1[jj]=fmaf(e10,f0[jj+dx],fmaf(e11,f1[jj+dx],a1[jj]));
      }
    }
  }
  int py=ty0+row;
  float wreg = t[19];
  size_t base=(size_t)py*W_ + tx0 + c4;
  if (outPlanar){
#pragma unroll
    for(int jj=0;jj<4;jj++){
      float2 rv=res[base+jj];
      float xr_=xt0[(row+2)*CT_S+c4+jj+2];
      float xi_=xt1[(row+2)*CT_S+c4+jj+2];
      outPlanar[base+jj]      = xr_ - wreg*rv.x - a0[jj];
      outPlanar[HW_+base+jj]  = xi_ - wreg*rv.y - a1[jj];
    }
  } else {
#pragma unroll
    for(int jj=0;jj<4;jj++){
      float2 rv=res[base+jj];
      float xr_=xt0[(row+2)*CT_S+c4+jj+2];
      float xi_=xt1[(row+2)*CT_S+c4+jj+2];
      xout[base+jj]=make_float2(xr_ - wreg*rv.x - a0[jj],
                                xi_ - wreg*rv.y - a1[jj]);
    }
  }
}

// border ring: exact conv2(conv1) with h zero-masked outside image
__global__ __launch_bounds__(256) void k_cnnb(const float2* __restrict__ x, const float2* __restrict__ res,
    const float* __restrict__ ec, const float* __restrict__ t,
    float2* __restrict__ xout, float* __restrict__ outPlanar){
  int id = blockIdx.x*256+threadIdx.x;   // 4096
  int py,px;
  if (id<1024){ py=0; px=id; }
  else if(id<2048){ py=1023; px=id-1024; }
  else if(id<3072){ py=id-2048; px=0; }
  else { py=id-3072; px=1023; }
  float s0=ec[444], s1=ec[445];
  for(int uy=0;uy<3;uy++){
    int qy=py+uy-1; if((unsigned)qy>=1024u) continue;
    for(int ux=0;ux<3;ux++){
      int qx=px+ux-1; if((unsigned)qx>=1024u) continue;
      int u=uy*3+ux;
      s0+=ec[102+u]; s1+=ec[111+u];
      const float* B0=&ec[120+u*18];
      const float* B1=&ec[282+u*18];
      for(int vy=0;vy<3;vy++){
        int sy2=qy+vy-1; if((unsigned)sy2>=1024u) continue;
        for(int vx=0;vx<3;vx++){
          int sx2=qx+vx-1; if((unsigned)sx2>=1024u) continue;
          int v=vy*3+vx;
          float2 xv=x[(size_t)sy2*W_+sx2];
          s0 = fmaf(B0[v],xv.x,fmaf(B0[9+v],xv.y,s0));
          s1 = fmaf(B1[v],xv.x,fmaf(B1[9+v],xv.y,s1));
        }
      }
    }
  }
  float wreg=t[19];
  size_t base=(size_t)py*W_+px;
  float2 xv=x[base], rv=res[base];
  float o0=xv.x - wreg*rv.x - s0;
  float o1=xv.y - wreg*rv.y - s1;
  if (outPlanar){ outPlanar[base]=o0; outPlanar[HW_+base]=o1; }
  else          { xout[base]=make_float2(o0,o1); }
}

// ================================================================ launch
extern "C" void kernel_launch(void* const* d_in, const int* in_sizes, int n_in,
                              void* d_out, int out_size, void* d_ws, size_t ws_size,
                              hipStream_t stream){
  (void)in_sizes; (void)n_in; (void)out_size; (void)ws_size;
  const float* xr  =(const float*)d_in[0];
  const float* xi  =(const float*)d_in[1];
  const float* kre =(const float*)d_in[2];
  const float* kim =(const float*)d_in[3];
  const float* kt  =(const float*)d_in[4];
  const float* wraw=(const float*)d_in[5];
  const float* w1  =(const float*)d_in[6];
  const float* b1  =(const float*)d_in[7];
  const float* w2  =(const float*)d_in[8];
  const float* b2  =(const float*)d_in[9];
  float* out = (float*)d_out;

  char* ws=(char*)d_ws;
  float2* Wx0 =(float2*)(ws);                      // 8MB
  float2* Wx1 =(float2*)(ws + ((size_t) 8<<20));   // 8MB
  int*   counts=(int*)   (ws + ((size_t) 8<<20));  // 4MB alias of Wx1 (setup only)
  int*   srcIdx=(int*)   (ws + ((size_t)12<<20));  // 2MB alias of Wx1 tail (setup only)
  float2* WF  =(float2*)(ws + ((size_t)16<<20));   // 8MB
  float2* kdat=(float2*)(ws + ((size_t)24<<20));   // 4MB
  float2* stat=(float2*)(ws + ((size_t)28<<20));   // 4MB
  float2* ysub=(float2*)(ws + ((size_t)32<<20));   // 4MB
  int*  cellA =(int*)   (ws + ((size_t)36<<20));   // 2MB
  int*  off   =(int*)   (ws + ((size_t)38<<20));   // 4MB
  int*  bsum  =(int*)   (ws + ((size_t)42<<20));   // 4KB
  float* t    =(float*) (ws + ((size_t)42<<20) + 8192);
  float* ec   =(float*) (ws + ((size_t)42<<20) + 16384);
  float* part =(float*) (ws + ((size_t)42<<20) + 32768);
  float* part2=(float*) (ws + ((size_t)42<<20) + 40960);
  float* pmax =(float*) (ws + ((size_t)42<<20) + 49152);
  const float SC = 0.03125f;   // 1/32 per 1-D ortho pass

  // ---- setup
  k_pack<<<HW_/256,256,0,stream>>>(xr,xi,Wx0,t);
  k_mkE<<<1,256,0,stream>>>(w1,b1,w2,b2,ec);
  hipMemsetAsync(counts,0,(size_t)HW_*sizeof(int),stream);
  k_hist<<<M_/256,256,0,stream>>>(kt,counts,pmax);
  k_reduce_max<<<1,256,0,stream>>>(pmax,t);
  k_scan1<<<1024,256,0,stream>>>(counts,off,bsum);
  k_scan2<<<1,256,0,stream>>>(bsum);
  k_scan3<<<1024,256,0,stream>>>(off,bsum);
  k_reorder1<<<M_/256,256,0,stream>>>(kt,off,srcIdx);
  k_reorder2<<<M_/256,256,0,stream>>>(srcIdx,kt,kre,kim,stat,cellA,ysub,kdat,t);

  // ---- power iteration, fully in k-space (fft2/ifft2 cancel; Parseval for norms)
  for (int n=0;n<9;n++){
    k_adj<<<HW_/1024,256,0,stream>>>(stat,kdat,off,WF,t,n);
    k_fwd_pow<<<M_/256,256,0,stream>>>(WF,cellA,stat,kdat,part,part2,(n==8)?1:0);
    if (n<8) k_reduce_chain<<<1,256,0,stream>>>(part,t,n);
    else     k_reduce_last <<<1,256,0,stream>>>(part,part2,wraw,t);
  }

  // ---- npcg = 4 PGD iterations
  for (int it=0; it<4; it++){
    float2* xin  = (it&1)? Wx1 : Wx0;
    float2* xout = (it&1)? Wx0 : Wx1;
    float* planar = (it==3)? out : (float*)nullptr;
    k_fft_rows<-1><<<H_,256,0,stream>>>(xin,WF,SC);
    k_fft_cols<-1><<<W_/4,256,0,stream>>>(WF,SC);
    k_fwd_sub<<<M_/256,256,0,stream>>>(WF,cellA,stat,ysub,kdat);
    k_adj<<<HW_/1024,256,0,stream>>>(stat,kdat,off,WF,t,-1);
    k_fft_rows<1><<<H_,256,0,stream>>>(WF,WF,SC);
    k_fft_cols<1><<<W_/4,256,0,stream>>>(WF,SC);
    k_cnn5<<<1024,256,0,stream>>>(xin,WF,ec,t,xout,planar);
    k_cnnb<<<16,256,0,stream>>>(xin,WF,ec,t,xout,planar);
  }
}